// Round 1
// baseline (960.411 us; speedup 1.0000x reference)
//
#include <hip/hip_runtime.h>
#include <math.h>

// Problem constants
#define NB    64
#define NN    256
#define NNODE 16384      // NB*NN
#define DD    512
#define HH    8
#define HDIM  64
#define NE    262144
#define BNEPS 1e-5f

// ---------------- workspace layout (4-byte units) ----------------
// Requires ws_size >= ~171 MB.
#define OFF_Q    0ull
#define OFF_K    8388608ull
#define OFF_V    16777216ull
#define OFF_XL   25165824ull
#define OFF_ACC  33554432ull
#define OFF_DEG  41943040ull
#define OFF_CS   (OFF_DEG + NNODE)
#define OFF_CSQ  (OFF_CS + DD)
#define OFF_CNT  (OFF_CSQ + DD)
#define OFF_CUR  (OFF_CNT + NNODE)
#define NZERO    (NNODE + DD + DD + NNODE + NNODE)
#define OFF_DINV (OFF_CUR + NNODE)
#define OFF_RP   (OFF_DINV + NNODE)
#define OFF_CSRC (OFF_RP + NNODE + 1)
#define OFF_CNRM (OFF_CSRC + NE)

// =====================================================================
// GEMM: C[16384x512] = A[16384x512] @ W[512x512] (+ bias)
// 64x64 tile, BK=32, 256 threads, 4x4 per-thread, transposed-A LDS.
// =====================================================================
__global__ __launch_bounds__(256) void k_gemm(const float* __restrict__ A,
                                              const float* __restrict__ W,
                                              const float* __restrict__ bias,
                                              float* __restrict__ C) {
  __shared__ float Ast[32][68];  // [k][row], pad 68 -> conflict-free b128 reads
  __shared__ float Bs[32][64];   // [k][col]
  const int tid = threadIdx.x;
  const int ty = tid >> 4, tx = tid & 15;
  const int row0 = blockIdx.y << 6;
  const int col0 = blockIdx.x << 6;
  // staging maps
  const int ar = tid >> 2;            // 0..63
  const int akb = (tid & 3) << 3;     // 0,8,16,24
  const int bkk = tid >> 3;           // 0..31
  const int bnb = (tid & 7) << 3;     // 0..56
  float acc[4][4] = {};
  for (int k0 = 0; k0 < DD; k0 += 32) {
    __syncthreads();
    {
      const float* ap = A + (size_t)(row0 + ar) * DD + k0 + akb;
      float4 a0 = *(const float4*)(ap);
      float4 a1 = *(const float4*)(ap + 4);
      Ast[akb + 0][ar] = a0.x; Ast[akb + 1][ar] = a0.y;
      Ast[akb + 2][ar] = a0.z; Ast[akb + 3][ar] = a0.w;
      Ast[akb + 4][ar] = a1.x; Ast[akb + 5][ar] = a1.y;
      Ast[akb + 6][ar] = a1.z; Ast[akb + 7][ar] = a1.w;
      const float* bp = W + (size_t)(k0 + bkk) * DD + col0 + bnb;
      *(float4*)(&Bs[bkk][bnb]) = *(const float4*)(bp);
      *(float4*)(&Bs[bkk][bnb + 4]) = *(const float4*)(bp + 4);
    }
    __syncthreads();
#pragma unroll
    for (int kk = 0; kk < 32; ++kk) {
      float4 af = *(const float4*)(&Ast[kk][ty << 2]);
      float4 bf = *(const float4*)(&Bs[kk][tx << 2]);
      float a4[4] = {af.x, af.y, af.z, af.w};
      float b4[4] = {bf.x, bf.y, bf.z, bf.w};
#pragma unroll
      for (int i = 0; i < 4; ++i)
#pragma unroll
        for (int j = 0; j < 4; ++j) acc[i][j] = fmaf(a4[i], b4[j], acc[i][j]);
    }
  }
  float4 bb = make_float4(0.f, 0.f, 0.f, 0.f);
  if (bias) bb = *(const float4*)(bias + col0 + (tx << 2));
#pragma unroll
  for (int i = 0; i < 4; ++i) {
    float4 o;
    o.x = acc[i][0] + bb.x; o.y = acc[i][1] + bb.y;
    o.z = acc[i][2] + bb.z; o.w = acc[i][3] + bb.w;
    *(float4*)(C + (size_t)(row0 + (ty << 2) + i) * DD + col0 + (tx << 2)) = o;
  }
}

// =====================================================================
// Attention: per (b,h,qblock of 64 rows), flash-style online softmax.
// ACC[row, h*64+d] += softmax(QK^T/8) @ V
// =====================================================================
__global__ __launch_bounds__(256) void k_attn(const float* __restrict__ Q,
                                              const float* __restrict__ K,
                                              const float* __restrict__ V,
                                              float* __restrict__ ACC) {
  __shared__ float Qt[64][68];   // [d][qrow] (pre-scaled by 1/8)
  __shared__ float KVt[64][68];  // K phase: [d][krow]; V phase: [krow][d]
  __shared__ float Ss[64][68];   // P tile: [qrow][k]
  const int tid = threadIdx.x;
  const int ty = tid >> 4, tx = tid & 15;
  const int bh = blockIdx.x;   // 512
  const int qb = blockIdx.y;   // 4
  const int b = bh >> 3, h = bh & 7;
  const size_t hoff = (size_t)h * HDIM;
  const int sr = tid >> 2;           // 0..63
  const int sd = (tid & 3) << 4;     // 0,16,32,48
  {
    const float* qsrc = Q + (size_t)(b * NN + qb * 64 + sr) * DD + hoff + sd;
#pragma unroll
    for (int c = 0; c < 4; ++c) {
      float4 v = *(const float4*)(qsrc + 4 * c);
      Qt[sd + 4 * c + 0][sr] = v.x * 0.125f;
      Qt[sd + 4 * c + 1][sr] = v.y * 0.125f;
      Qt[sd + 4 * c + 2][sr] = v.z * 0.125f;
      Qt[sd + 4 * c + 3][sr] = v.w * 0.125f;
    }
  }
  float o[4][4] = {};
  float m[4] = {-INFINITY, -INFINITY, -INFINITY, -INFINITY};
  float l[4] = {0.f, 0.f, 0.f, 0.f};
  for (int kt = 0; kt < 4; ++kt) {
    __syncthreads();  // Qt staged (first iter) / prev PV reads of KVt done
    {
      const float* ksrc = K + (size_t)(b * NN + kt * 64 + sr) * DD + hoff + sd;
#pragma unroll
      for (int c = 0; c < 4; ++c) {
        float4 v = *(const float4*)(ksrc + 4 * c);
        KVt[sd + 4 * c + 0][sr] = v.x;
        KVt[sd + 4 * c + 1][sr] = v.y;
        KVt[sd + 4 * c + 2][sr] = v.z;
        KVt[sd + 4 * c + 3][sr] = v.w;
      }
    }
    __syncthreads();
    float s[4][4] = {};
#pragma unroll
    for (int d = 0; d < 64; ++d) {
      float4 af = *(const float4*)(&Qt[d][ty << 2]);
      float4 bf = *(const float4*)(&KVt[d][tx << 2]);
      float a4[4] = {af.x, af.y, af.z, af.w};
      float b4[4] = {bf.x, bf.y, bf.z, bf.w};
#pragma unroll
      for (int i = 0; i < 4; ++i)
#pragma unroll
        for (int j = 0; j < 4; ++j) s[i][j] = fmaf(a4[i], b4[j], s[i][j]);
    }
#pragma unroll
    for (int i = 0; i < 4; ++i) {
      float mt = fmaxf(fmaxf(s[i][0], s[i][1]), fmaxf(s[i][2], s[i][3]));
#pragma unroll
      for (int off = 1; off < 16; off <<= 1) mt = fmaxf(mt, __shfl_xor(mt, off, 64));
      float mn = fmaxf(m[i], mt);
      float sc = __expf(m[i] - mn);
      float rs = 0.f;
#pragma unroll
      for (int j = 0; j < 4; ++j) { s[i][j] = __expf(s[i][j] - mn); rs += s[i][j]; }
#pragma unroll
      for (int off = 1; off < 16; off <<= 1) rs += __shfl_xor(rs, off, 64);
      l[i] = l[i] * sc + rs;
      m[i] = mn;
#pragma unroll
      for (int dd = 0; dd < 4; ++dd) o[i][dd] *= sc;
      *(float4*)(&Ss[(ty << 2) + i][tx << 2]) = make_float4(s[i][0], s[i][1], s[i][2], s[i][3]);
    }
    __syncthreads();  // Ss written; K reads of KVt done -> safe to overwrite with V
    {
      const float* vsrc = V + (size_t)(b * NN + kt * 64 + sr) * DD + hoff + sd;
#pragma unroll
      for (int c = 0; c < 4; ++c)
        *(float4*)(&KVt[sr][sd + 4 * c]) = *(const float4*)(vsrc + 4 * c);
    }
    __syncthreads();
#pragma unroll
    for (int k4 = 0; k4 < 16; ++k4) {
      float4 p0 = *(const float4*)(&Ss[(ty << 2) + 0][k4 << 2]);
      float4 p1 = *(const float4*)(&Ss[(ty << 2) + 1][k4 << 2]);
      float4 p2 = *(const float4*)(&Ss[(ty << 2) + 2][k4 << 2]);
      float4 p3 = *(const float4*)(&Ss[(ty << 2) + 3][k4 << 2]);
      float pa[4][4] = {{p0.x, p0.y, p0.z, p0.w},
                        {p1.x, p1.y, p1.z, p1.w},
                        {p2.x, p2.y, p2.z, p2.w},
                        {p3.x, p3.y, p3.z, p3.w}};
#pragma unroll
      for (int kk = 0; kk < 4; ++kk) {
        float4 vf = *(const float4*)(&KVt[(k4 << 2) + kk][tx << 2]);
        float v4[4] = {vf.x, vf.y, vf.z, vf.w};
#pragma unroll
        for (int i = 0; i < 4; ++i)
#pragma unroll
          for (int dd = 0; dd < 4; ++dd) o[i][dd] = fmaf(pa[i][kk], v4[dd], o[i][dd]);
      }
    }
  }
#pragma unroll
  for (int i = 0; i < 4; ++i) {
    float inv = 1.f / l[i];
    float* dst = ACC + (size_t)(b * NN + qb * 64 + (ty << 2) + i) * DD + hoff + (tx << 2);
    float4 cur = *(const float4*)dst;
    cur.x += o[i][0] * inv; cur.y += o[i][1] * inv;
    cur.z += o[i][2] * inv; cur.w += o[i][3] * inv;
    *(float4*)dst = cur;
  }
}

// =====================================================================
// GCN plumbing
// =====================================================================
__global__ __launch_bounds__(256) void k_degcnt(const int* __restrict__ ei,
                                                const float* __restrict__ w,
                                                float* __restrict__ deg,
                                                int* __restrict__ cnt) {
  int e = blockIdx.x * 256 + threadIdx.x;
  if (e < NE) {
    int d = ei[NE + e];
    atomicAdd(deg + d, w[e]);
    atomicAdd(cnt + d, 1);
  }
}

__global__ __launch_bounds__(256) void k_dinv(const float* __restrict__ deg,
                                              float* __restrict__ dinv) {
  int i = blockIdx.x * 256 + threadIdx.x;
  if (i < NNODE) dinv[i] = rsqrtf(deg[i] + 1.0f);  // +1 = self-loop weight
}

// single-block exclusive scan of cnt[16384] -> rowptr[16385]
__global__ __launch_bounds__(256) void k_scan(const int* __restrict__ cnt,
                                              int* __restrict__ rowptr) {
  __shared__ int part[256];
  __shared__ int excl[257];
  const int t = threadIdx.x;
  const int base = t * 64;
  int s = 0;
  for (int j = 0; j < 64; ++j) s += cnt[base + j];
  part[t] = s;
  __syncthreads();
  if (t == 0) {
    int run = 0;
    for (int i = 0; i < 256; ++i) { excl[i] = run; run += part[i]; }
    excl[256] = run;
  }
  __syncthreads();
  int run = excl[t];
  for (int j = 0; j < 64; ++j) { rowptr[base + j] = run; run += cnt[base + j]; }
  if (t == 255) rowptr[NNODE] = excl[256];
}

__global__ __launch_bounds__(256) void k_fill(const int* __restrict__ ei,
                                              const float* __restrict__ w,
                                              const float* __restrict__ dinv,
                                              const int* __restrict__ rowptr,
                                              int* __restrict__ cursor,
                                              int* __restrict__ csrc,
                                              float* __restrict__ cnrm) {
  int e = blockIdx.x * 256 + threadIdx.x;
  if (e >= NE) return;
  int s = ei[e], d = ei[NE + e];
  int p = rowptr[d] + atomicAdd(cursor + d, 1);
  csrc[p] = s;
  cnrm[p] = dinv[s] * w[e] * dinv[d];
}

// per-node CSR aggregate; folds self-loop (dinv^2 * xl) and bg; RMW into ACC.
__global__ __launch_bounds__(256) void k_aggregate(const int* __restrict__ rowptr,
                                                   const int* __restrict__ csrc,
                                                   const float* __restrict__ cnrm,
                                                   const float* __restrict__ XL,
                                                   const float* __restrict__ dinv,
                                                   const float* __restrict__ bg,
                                                   float* __restrict__ ACC) {
  const int node = blockIdx.x * 2 + (threadIdx.x >> 7);
  const int c0 = (threadIdx.x & 127) << 2;
  float dv = dinv[node];
  dv *= dv;
  float4 a = *(const float4*)(XL + (size_t)node * DD + c0);
  a.x *= dv; a.y *= dv; a.z *= dv; a.w *= dv;
  const int beg = rowptr[node], end = rowptr[node + 1];
  int j = beg;
  for (; j + 1 < end; j += 2) {  // 2-way unroll for MLP
    int s0 = csrc[j], s1 = csrc[j + 1];
    float n0 = cnrm[j], n1 = cnrm[j + 1];
    float4 u = *(const float4*)(XL + (size_t)s0 * DD + c0);
    float4 v = *(const float4*)(XL + (size_t)s1 * DD + c0);
    a.x = fmaf(u.x, n0, a.x); a.y = fmaf(u.y, n0, a.y);
    a.z = fmaf(u.z, n0, a.z); a.w = fmaf(u.w, n0, a.w);
    a.x = fmaf(v.x, n1, a.x); a.y = fmaf(v.y, n1, a.y);
    a.z = fmaf(v.z, n1, a.z); a.w = fmaf(v.w, n1, a.w);
  }
  if (j < end) {
    int s0 = csrc[j];
    float n0 = cnrm[j];
    float4 u = *(const float4*)(XL + (size_t)s0 * DD + c0);
    a.x = fmaf(u.x, n0, a.x); a.y = fmaf(u.y, n0, a.y);
    a.z = fmaf(u.z, n0, a.z); a.w = fmaf(u.w, n0, a.w);
  }
  float4 b = *(const float4*)(bg + c0);
  float* dst = ACC + (size_t)node * DD + c0;
  float4 c = *(const float4*)dst;
  c.x += a.x + b.x; c.y += a.y + b.y; c.z += a.z + b.z; c.w += a.w + b.w;
  *(float4*)dst = c;
}

// =====================================================================
// BatchNorm stats + finalize (BN + exact GELU)
// =====================================================================
__global__ __launch_bounds__(128) void k_colstats(const float* __restrict__ ACC,
                                                  float* __restrict__ cs,
                                                  float* __restrict__ csq) {
  const int col = blockIdx.y * 128 + threadIdx.x;
  const int r0 = blockIdx.x * 64;
  float s = 0.f, q = 0.f;
  for (int r = 0; r < 64; ++r) {
    float v = ACC[(size_t)(r0 + r) * DD + col];
    s += v;
    q = fmaf(v, v, q);
  }
  atomicAdd(cs + col, s);
  atomicAdd(csq + col, q);
}

__global__ __launch_bounds__(256) void k_finalize(const float* __restrict__ ACC,
                                                  const float* __restrict__ cs,
                                                  const float* __restrict__ csq,
                                                  const float* __restrict__ gamma,
                                                  const float* __restrict__ beta,
                                                  float* __restrict__ out) {
  const size_t i4 = (size_t)blockIdx.x * 256 + threadIdx.x;  // 2,097,152 float4s
  const int c = (int)(i4 & 127) << 2;
  float4 a = *(const float4*)(ACC + i4 * 4);
  float4 sv = *(const float4*)(cs + c);
  float4 qv = *(const float4*)(csq + c);
  float4 gv = *(const float4*)(gamma + c);
  float4 bv = *(const float4*)(beta + c);
  const float inv_n = 1.0f / (float)NNODE;
  float r[4];
  float av[4] = {a.x, a.y, a.z, a.w};
  float sa[4] = {sv.x, sv.y, sv.z, sv.w};
  float qa[4] = {qv.x, qv.y, qv.z, qv.w};
  float ga[4] = {gv.x, gv.y, gv.z, gv.w};
  float ba[4] = {bv.x, bv.y, bv.z, bv.w};
#pragma unroll
  for (int k = 0; k < 4; ++k) {
    float mu = sa[k] * inv_n;
    float var = qa[k] * inv_n - mu * mu;
    float g = (av[k] - mu) * rsqrtf(var + BNEPS) * ga[k] + ba[k];
    r[k] = 0.5f * g * (1.0f + erff(g * 0.70710678118654752f));  // exact GELU
  }
  *(float4*)(out + i4 * 4) = make_float4(r[0], r[1], r[2], r[3]);
}

// =====================================================================
extern "C" void kernel_launch(void* const* d_in, const int* in_sizes, int n_in,
                              void* d_out, int out_size, void* d_ws, size_t ws_size,
                              hipStream_t stream) {
  const float* x   = (const float*)d_in[0];
  const int*   ei  = (const int*)d_in[1];
  const float* w   = (const float*)d_in[2];
  // d_in[3] = batch_vec (unused: equal-size graphs)
  const float* Wq  = (const float*)d_in[4];
  const float* bq  = (const float*)d_in[5];
  const float* Wk  = (const float*)d_in[6];
  const float* bk  = (const float*)d_in[7];
  const float* Wv  = (const float*)d_in[8];
  const float* bv  = (const float*)d_in[9];
  const float* Wsk = (const float*)d_in[10];
  const float* bs  = (const float*)d_in[11];
  const float* Wg  = (const float*)d_in[12];
  const float* bg  = (const float*)d_in[13];
  const float* gam = (const float*)d_in[14];
  const float* bet = (const float*)d_in[15];

  float* wsf = (float*)d_ws;
  float* Qb   = wsf + OFF_Q;
  float* Kb   = wsf + OFF_K;
  float* Vb   = wsf + OFF_V;
  float* XL   = wsf + OFF_XL;
  float* ACC  = wsf + OFF_ACC;
  float* DEG  = wsf + OFF_DEG;
  float* CS   = wsf + OFF_CS;
  float* CSQ  = wsf + OFF_CSQ;
  int*   CNT  = (int*)(wsf + OFF_CNT);
  int*   CUR  = (int*)(wsf + OFF_CUR);
  float* DINV = wsf + OFF_DINV;
  int*   RP   = (int*)(wsf + OFF_RP);
  int*   CSRC = (int*)(wsf + OFF_CSRC);
  float* CNRM = wsf + OFF_CNRM;

  // zero deg/colstats/cnt/cursor (ws is poisoned 0xAA before every call)
  hipMemsetAsync(wsf + OFF_DEG, 0, (size_t)NZERO * 4, stream);

  dim3 gg(DD / 64, NNODE / 64);  // (8, 256)
  k_gemm<<<gg, 256, 0, stream>>>(x, Wq, bq, Qb);
  k_gemm<<<gg, 256, 0, stream>>>(x, Wk, bk, Kb);
  k_gemm<<<gg, 256, 0, stream>>>(x, Wv, bv, Vb);
  k_gemm<<<gg, 256, 0, stream>>>(x, Wsk, bs, ACC);   // skip path initializes ACC
  k_gemm<<<gg, 256, 0, stream>>>(x, Wg, nullptr, XL);

  k_degcnt<<<NE / 256, 256, 0, stream>>>(ei, w, DEG, CNT);
  k_dinv<<<NNODE / 256, 256, 0, stream>>>(DEG, DINV);
  k_scan<<<1, 256, 0, stream>>>(CNT, RP);
  k_fill<<<NE / 256, 256, 0, stream>>>(ei, w, DINV, RP, CUR, CSRC, CNRM);

  k_attn<<<dim3(NB * HH, NN / 64), 256, 0, stream>>>(Qb, Kb, Vb, ACC);
  k_aggregate<<<NNODE / 2, 256, 0, stream>>>(RP, CSRC, CNRM, XL, DINV, bg, ACC);

  k_colstats<<<dim3(NNODE / 64, DD / 128), 128, 0, stream>>>(ACC, CS, CSQ);
  k_finalize<<<(NNODE * DD / 4) / 256, 256, 0, stream>>>(ACC, CS, CSQ, gam, bet, (float*)d_out);
}

// Round 3
// 672.732 us; speedup vs baseline: 1.4276x; 1.4276x over previous
//
#include <hip/hip_runtime.h>
#include <math.h>

// Problem constants
#define NB    64
#define NN    256
#define NNODE 16384      // NB*NN
#define DD    512
#define HH    8
#define HDIM  64
#define NE    262144
#define BNEPS 1e-5f
#define K3    1536       // split-bf16 interleaved K (3 * 512)
#define KSTEPS 48        // K3 / 32

// ---------------- workspace layout (4-byte units) ----------------
#define OFF_Q    0ull
#define OFF_K    8388608ull
#define OFF_V    16777216ull
#define OFF_XL   25165824ull
#define OFF_ACC  33554432ull
#define OFF_DEG  41943040ull
#define OFF_CS   (OFF_DEG + NNODE)
#define OFF_CSQ  (OFF_CS + DD)
#define OFF_CNT  (OFF_CSQ + DD)
#define OFF_CUR  (OFF_CNT + NNODE)
#define NZERO    (NNODE + DD + DD + NNODE + NNODE)
#define OFF_DINV (OFF_CUR + NNODE)
#define OFF_RP   (OFF_DINV + NNODE)
#define OFF_CSRC (OFF_RP + NNODE + 1)
#define OFF_CNRM (OFF_CSRC + NE)
#define OFF_AP   42550280ull                  // 16B aligned; bf16 A' [16384][1536]
#define OFF_WP   (OFF_AP + 12582912ull)       // bf16 W'  [5][512][1536]
#define WS_NEED_MFMA ((OFF_WP + 1966080ull) * 4ull)   // ~228.4 MB

typedef __attribute__((ext_vector_type(8))) short bf16x8;
typedef __attribute__((ext_vector_type(4))) float f32x4;

__device__ __forceinline__ ushort bf16rn(float v) {
  uint u = __float_as_uint(v);
  u += 0x7FFF + ((u >> 16) & 1);
  return (ushort)(u >> 16);
}

// =====================================================================
// fp32 -> split-bf16 conversions
// A'[m][3k+0]=hi(x[m][k]) [3k+1]=lo [3k+2]=hi
// =====================================================================
__global__ __launch_bounds__(256) void k_cvtA(const float* __restrict__ x,
                                              ushort* __restrict__ Ap) {
  const size_t t = (size_t)blockIdx.x * 256 + threadIdx.x;  // 1,048,576 threads
  const int row = (int)(t >> 6);
  const int kc = (int)(t & 63);  // chunk of 8 k-values
  const float* src = x + (size_t)row * DD + kc * 8;
  float4 v0 = *(const float4*)(src);
  float4 v1 = *(const float4*)(src + 4);
  float vv[8] = {v0.x, v0.y, v0.z, v0.w, v1.x, v1.y, v1.z, v1.w};
  ushort o[24];
#pragma unroll
  for (int j = 0; j < 8; ++j) {
    float v = vv[j];
    ushort h = bf16rn(v);
    float hf = __uint_as_float((uint)h << 16);
    ushort l = bf16rn(v - hf);
    o[3 * j] = h; o[3 * j + 1] = l; o[3 * j + 2] = h;
  }
  uint uu[12];
#pragma unroll
  for (int i = 0; i < 12; ++i) uu[i] = (uint)o[2 * i] | ((uint)o[2 * i + 1] << 16);
  uint4* dst = (uint4*)(Ap + (size_t)row * K3 + kc * 24);
  dst[0] = make_uint4(uu[0], uu[1], uu[2], uu[3]);
  dst[1] = make_uint4(uu[4], uu[5], uu[6], uu[7]);
  dst[2] = make_uint4(uu[8], uu[9], uu[10], uu[11]);
}

// W[k][n] -> W'[n][3k+0]=hi [3k+1]=hi [3k+2]=lo   (transposed, per weight z)
__global__ __launch_bounds__(256) void k_cvtW(const float* __restrict__ W0,
                                              const float* __restrict__ W1,
                                              const float* __restrict__ W2,
                                              const float* __restrict__ W3,
                                              const float* __restrict__ W4,
                                              ushort* __restrict__ Wp) {
  __shared__ float Wl[64][65];
  const float* const Wt[5] = {W0, W1, W2, W3, W4};
  const float* W = Wt[blockIdx.z];
  ushort* dst_base = Wp + (size_t)blockIdx.z * (DD * K3);
  const int k0 = blockIdx.x * 64, n0 = blockIdx.y * 64;
  const int tid = threadIdx.x;
#pragma unroll
  for (int i = 0; i < 4; ++i) {
    int r = (tid >> 4) + i * 16;
    int c4 = (tid & 15) * 4;
    float4 v = *(const float4*)(W + (size_t)(k0 + r) * DD + n0 + c4);
    Wl[r][c4 + 0] = v.x; Wl[r][c4 + 1] = v.y; Wl[r][c4 + 2] = v.z; Wl[r][c4 + 3] = v.w;
  }
  __syncthreads();
  const int nl = tid >> 2;
  const int kc = (tid & 3) * 16;
  ushort o[48];
#pragma unroll
  for (int j = 0; j < 16; ++j) {
    float v = Wl[kc + j][nl];
    ushort h = bf16rn(v);
    float hf = __uint_as_float((uint)h << 16);
    ushort l = bf16rn(v - hf);
    o[3 * j] = h; o[3 * j + 1] = h; o[3 * j + 2] = l;
  }
  uint uu[24];
#pragma unroll
  for (int i = 0; i < 24; ++i) uu[i] = (uint)o[2 * i] | ((uint)o[2 * i + 1] << 16);
  uint4* dst = (uint4*)(dst_base + (size_t)(n0 + nl) * K3 + (size_t)(k0 + kc) * 3);
#pragma unroll
  for (int i = 0; i < 6; ++i)
    dst[i] = make_uint4(uu[4 * i], uu[4 * i + 1], uu[4 * i + 2], uu[4 * i + 3]);
}

// =====================================================================
// MFMA GEMM: C[16384x512] = A'[16384xK3] @ W'[512xK3]^T (+bias)
// 128x128 tile, BK=32, 256 thr (4 waves, 2x2), 4x4 frags of 16x16x32 bf16.
// Double-buffered LDS via global_load_lds(16B), one barrier per K-step.
// =====================================================================
__global__ __launch_bounds__(256) void k_gemm_mfma(const ushort* __restrict__ Ap,
                                                   const ushort* __restrict__ Bp,
                                                   const float* __restrict__ bias,
                                                   float* __restrict__ C) {
  __shared__ ushort Asm[2][128][32];
  __shared__ ushort Bsm[2][128][32];
  const int tid = threadIdx.x;
  const int lane = tid & 63;
  const int wv = tid >> 6;            // wave 0..3
  const int row0 = blockIdx.y * 128;
  const int col0 = blockIdx.x * 128;
  const int srow = lane >> 2;         // staging row within 16-row chunk
  const int sk8 = (lane & 3) * 8;     // staging k-element offset
  const int lane16 = lane & 15;
  const int lq = lane >> 4;           // 0..3
  const int wm = (wv >> 1) * 64;
  const int wn = (wv & 1) * 64;

#define STAGE(buf, t)                                                                   \
  do {                                                                                  \
    const int k0s = (t) * 32;                                                           \
    _Pragma("unroll") for (int c = wv; c < 8; c += 4) {                                 \
      const ushort* ga = Ap + (size_t)(row0 + c * 16 + srow) * K3 + k0s + sk8;          \
      __builtin_amdgcn_global_load_lds(                                                 \
          (const __attribute__((address_space(1))) void*)ga,                            \
          (__attribute__((address_space(3))) void*)&Asm[buf][c * 16][0], 16, 0, 0);     \
      const ushort* gb = Bp + (size_t)(col0 + c * 16 + srow) * K3 + k0s + sk8;          \
      __builtin_amdgcn_global_load_lds(                                                 \
          (const __attribute__((address_space(1))) void*)gb,                            \
          (__attribute__((address_space(3))) void*)&Bsm[buf][c * 16][0], 16, 0, 0);     \
    }                                                                                   \
  } while (0)

  f32x4 acc[4][4];
#pragma unroll
  for (int m = 0; m < 4; ++m)
#pragma unroll
    for (int n = 0; n < 4; ++n) acc[m][n] = (f32x4){0.f, 0.f, 0.f, 0.f};

  STAGE(0, 0);
  int cur = 0;
  for (int t = 0; t < KSTEPS; ++t) {
    __syncthreads();  // drains vmcnt: staged tile t visible; prev reads done
    if (t + 1 < KSTEPS) STAGE(cur ^ 1, t + 1);
    bf16x8 av[4], bv[4];
#pragma unroll
    for (int m = 0; m < 4; ++m)
      av[m] = *(const bf16x8*)&Asm[cur][wm + m * 16 + lane16][lq * 8];
#pragma unroll
    for (int n = 0; n < 4; ++n)
      bv[n] = *(const bf16x8*)&Bsm[cur][wn + n * 16 + lane16][lq * 8];
#pragma unroll
    for (int m = 0; m < 4; ++m)
#pragma unroll
      for (int n = 0; n < 4; ++n)
        acc[m][n] = __builtin_amdgcn_mfma_f32_16x16x32_bf16(av[m], bv[n], acc[m][n], 0, 0, 0);
    cur ^= 1;
  }
#pragma unroll
  for (int n = 0; n < 4; ++n) {
    const int col = col0 + wn + n * 16 + lane16;
    const float bb = bias ? bias[col] : 0.0f;
#pragma unroll
    for (int m = 0; m < 4; ++m) {
      const int row = row0 + wm + m * 16 + lq * 4;
#pragma unroll
      for (int r = 0; r < 4; ++r)
        C[(size_t)(row + r) * DD + col] = acc[m][n][r] + bb;
    }
  }
#undef STAGE
}

// =====================================================================
// fp32 fallback GEMM (proven in R1): 64x64 tile, BK=32, 4x4/thread.
// =====================================================================
__global__ __launch_bounds__(256) void k_gemm(const float* __restrict__ A,
                                              const float* __restrict__ W,
                                              const float* __restrict__ bias,
                                              float* __restrict__ C) {
  __shared__ float Ast[32][68];
  __shared__ float Bs[32][64];
  const int tid = threadIdx.x;
  const int ty = tid >> 4, tx = tid & 15;
  const int row0 = blockIdx.y << 6;
  const int col0 = blockIdx.x << 6;
  const int ar = tid >> 2;
  const int akb = (tid & 3) << 3;
  const int bkk = tid >> 3;
  const int bnb = (tid & 7) << 3;
  float acc[4][4] = {};
  for (int k0 = 0; k0 < DD; k0 += 32) {
    __syncthreads();
    {
      const float* ap = A + (size_t)(row0 + ar) * DD + k0 + akb;
      float4 a0 = *(const float4*)(ap);
      float4 a1 = *(const float4*)(ap + 4);
      Ast[akb + 0][ar] = a0.x; Ast[akb + 1][ar] = a0.y;
      Ast[akb + 2][ar] = a0.z; Ast[akb + 3][ar] = a0.w;
      Ast[akb + 4][ar] = a1.x; Ast[akb + 5][ar] = a1.y;
      Ast[akb + 6][ar] = a1.z; Ast[akb + 7][ar] = a1.w;
      const float* bp = W + (size_t)(k0 + bkk) * DD + col0 + bnb;
      *(float4*)(&Bs[bkk][bnb]) = *(const float4*)(bp);
      *(float4*)(&Bs[bkk][bnb + 4]) = *(const float4*)(bp + 4);
    }
    __syncthreads();
#pragma unroll
    for (int kk = 0; kk < 32; ++kk) {
      float4 af = *(const float4*)(&Ast[kk][ty << 2]);
      float4 bf = *(const float4*)(&Bs[kk][tx << 2]);
      float a4[4] = {af.x, af.y, af.z, af.w};
      float b4[4] = {bf.x, bf.y, bf.z, bf.w};
#pragma unroll
      for (int i = 0; i < 4; ++i)
#pragma unroll
        for (int j = 0; j < 4; ++j) acc[i][j] = fmaf(a4[i], b4[j], acc[i][j]);
    }
  }
  float4 bb = make_float4(0.f, 0.f, 0.f, 0.f);
  if (bias) bb = *(const float4*)(bias + col0 + (tx << 2));
#pragma unroll
  for (int i = 0; i < 4; ++i) {
    float4 o;
    o.x = acc[i][0] + bb.x; o.y = acc[i][1] + bb.y;
    o.z = acc[i][2] + bb.z; o.w = acc[i][3] + bb.w;
    *(float4*)(C + (size_t)(row0 + (ty << 2) + i) * DD + col0 + (tx << 2)) = o;
  }
}

// =====================================================================
// Attention: per (b,h,qblock of 64 rows), flash-style online softmax.
// ACC[row, h*64+d] += softmax(QK^T/8) @ V
// =====================================================================
__global__ __launch_bounds__(256) void k_attn(const float* __restrict__ Q,
                                              const float* __restrict__ K,
                                              const float* __restrict__ V,
                                              float* __restrict__ ACC) {
  __shared__ float Qt[64][68];
  __shared__ float KVt[64][68];
  __shared__ float Ss[64][68];
  const int tid = threadIdx.x;
  const int ty = tid >> 4, tx = tid & 15;
  const int bh = blockIdx.x;
  const int qb = blockIdx.y;
  const int b = bh >> 3, h = bh & 7;
  const size_t hoff = (size_t)h * HDIM;
  const int sr = tid >> 2;
  const int sd = (tid & 3) << 4;
  {
    const float* qsrc = Q + (size_t)(b * NN + qb * 64 + sr) * DD + hoff + sd;
#pragma unroll
    for (int c = 0; c < 4; ++c) {
      float4 v = *(const float4*)(qsrc + 4 * c);
      Qt[sd + 4 * c + 0][sr] = v.x * 0.125f;
      Qt[sd + 4 * c + 1][sr] = v.y * 0.125f;
      Qt[sd + 4 * c + 2][sr] = v.z * 0.125f;
      Qt[sd + 4 * c + 3][sr] = v.w * 0.125f;
    }
  }
  float o[4][4] = {};
  float m[4] = {-INFINITY, -INFINITY, -INFINITY, -INFINITY};
  float l[4] = {0.f, 0.f, 0.f, 0.f};
  for (int kt = 0; kt < 4; ++kt) {
    __syncthreads();
    {
      const float* ksrc = K + (size_t)(b * NN + kt * 64 + sr) * DD + hoff + sd;
#pragma unroll
      for (int c = 0; c < 4; ++c) {
        float4 v = *(const float4*)(ksrc + 4 * c);
        KVt[sd + 4 * c + 0][sr] = v.x;
        KVt[sd + 4 * c + 1][sr] = v.y;
        KVt[sd + 4 * c + 2][sr] = v.z;
        KVt[sd + 4 * c + 3][sr] = v.w;
      }
    }
    __syncthreads();
    float s[4][4] = {};
#pragma unroll
    for (int d = 0; d < 64; ++d) {
      float4 af = *(const float4*)(&Qt[d][ty << 2]);
      float4 bf = *(const float4*)(&KVt[d][tx << 2]);
      float a4[4] = {af.x, af.y, af.z, af.w};
      float b4[4] = {bf.x, bf.y, bf.z, bf.w};
#pragma unroll
      for (int i = 0; i < 4; ++i)
#pragma unroll
        for (int j = 0; j < 4; ++j) s[i][j] = fmaf(a4[i], b4[j], s[i][j]);
    }
#pragma unroll
    for (int i = 0; i < 4; ++i) {
      float mt = fmaxf(fmaxf(s[i][0], s[i][1]), fmaxf(s[i][2], s[i][3]));
#pragma unroll
      for (int off = 1; off < 16; off <<= 1) mt = fmaxf(mt, __shfl_xor(mt, off, 64));
      float mn = fmaxf(m[i], mt);
      float sc = __expf(m[i] - mn);
      float rs = 0.f;
#pragma unroll
      for (int j = 0; j < 4; ++j) { s[i][j] = __expf(s[i][j] - mn); rs += s[i][j]; }
#pragma unroll
      for (int off = 1; off < 16; off <<= 1) rs += __shfl_xor(rs, off, 64);
      l[i] = l[i] * sc + rs;
      m[i] = mn;
#pragma unroll
      for (int dd = 0; dd < 4; ++dd) o[i][dd] *= sc;
      *(float4*)(&Ss[(ty << 2) + i][tx << 2]) = make_float4(s[i][0], s[i][1], s[i][2], s[i][3]);
    }
    __syncthreads();
    {
      const float* vsrc = V + (size_t)(b * NN + kt * 64 + sr) * DD + hoff + sd;
#pragma unroll
      for (int c = 0; c < 4; ++c)
        *(float4*)(&KVt[sr][sd + 4 * c]) = *(const float4*)(vsrc + 4 * c);
    }
    __syncthreads();
#pragma unroll
    for (int k4 = 0; k4 < 16; ++k4) {
      float4 p0 = *(const float4*)(&Ss[(ty << 2) + 0][k4 << 2]);
      float4 p1 = *(const float4*)(&Ss[(ty << 2) + 1][k4 << 2]);
      float4 p2 = *(const float4*)(&Ss[(ty << 2) + 2][k4 << 2]);
      float4 p3 = *(const float4*)(&Ss[(ty << 2) + 3][k4 << 2]);
      float pa[4][4] = {{p0.x, p0.y, p0.z, p0.w},
                        {p1.x, p1.y, p1.z, p1.w},
                        {p2.x, p2.y, p2.z, p2.w},
                        {p3.x, p3.y, p3.z, p3.w}};
#pragma unroll
      for (int kk = 0; kk < 4; ++kk) {
        float4 vf = *(const float4*)(&KVt[(k4 << 2) + kk][tx << 2]);
        float v4[4] = {vf.x, vf.y, vf.z, vf.w};
#pragma unroll
        for (int i = 0; i < 4; ++i)
#pragma unroll
          for (int dd = 0; dd < 4; ++dd) o[i][dd] = fmaf(pa[i][kk], v4[dd], o[i][dd]);
      }
    }
  }
#pragma unroll
  for (int i = 0; i < 4; ++i) {
    float inv = 1.f / l[i];
    float* dst = ACC + (size_t)(b * NN + qb * 64 + (ty << 2) + i) * DD + hoff + (tx << 2);
    float4 cur = *(const float4*)dst;
    cur.x += o[i][0] * inv; cur.y += o[i][1] * inv;
    cur.z += o[i][2] * inv; cur.w += o[i][3] * inv;
    *(float4*)dst = cur;
  }
}

// =====================================================================
// GCN plumbing
// =====================================================================
__global__ __launch_bounds__(256) void k_degcnt(const int* __restrict__ ei,
                                                const float* __restrict__ w,
                                                float* __restrict__ deg,
                                                int* __restrict__ cnt) {
  int e = blockIdx.x * 256 + threadIdx.x;
  if (e < NE) {
    int d = ei[NE + e];
    atomicAdd(deg + d, w[e]);
    atomicAdd(cnt + d, 1);
  }
}

__global__ __launch_bounds__(256) void k_dinv(const float* __restrict__ deg,
                                              float* __restrict__ dinv) {
  int i = blockIdx.x * 256 + threadIdx.x;
  if (i < NNODE) dinv[i] = rsqrtf(deg[i] + 1.0f);
}

__global__ __launch_bounds__(256) void k_scan(const int* __restrict__ cnt,
                                              int* __restrict__ rowptr) {
  __shared__ int part[256];
  __shared__ int excl[257];
  const int t = threadIdx.x;
  const int base = t * 64;
  int s = 0;
  for (int j = 0; j < 64; ++j) s += cnt[base + j];
  part[t] = s;
  __syncthreads();
  if (t == 0) {
    int run = 0;
    for (int i = 0; i < 256; ++i) { excl[i] = run; run += part[i]; }
    excl[256] = run;
  }
  __syncthreads();
  int run = excl[t];
  for (int j = 0; j < 64; ++j) { rowptr[base + j] = run; run += cnt[base + j]; }
  if (t == 255) rowptr[NNODE] = excl[256];
}

__global__ __launch_bounds__(256) void k_fill(const int* __restrict__ ei,
                                              const float* __restrict__ w,
                                              const float* __restrict__ dinv,
                                              const int* __restrict__ rowptr,
                                              int* __restrict__ cursor,
                                              int* __restrict__ csrc,
                                              float* __restrict__ cnrm) {
  int e = blockIdx.x * 256 + threadIdx.x;
  if (e >= NE) return;
  int s = ei[e], d = ei[NE + e];
  int p = rowptr[d] + atomicAdd(cursor + d, 1);
  csrc[p] = s;
  cnrm[p] = dinv[s] * w[e] * dinv[d];
}

__global__ __launch_bounds__(256) void k_aggregate(const int* __restrict__ rowptr,
                                                   const int* __restrict__ csrc,
                                                   const float* __restrict__ cnrm,
                                                   const float* __restrict__ XL,
                                                   const float* __restrict__ dinv,
                                                   const float* __restrict__ bg,
                                                   float* __restrict__ ACC) {
  const int node = blockIdx.x * 2 + (threadIdx.x >> 7);
  const int c0 = (threadIdx.x & 127) << 2;
  float dv = dinv[node];
  dv *= dv;
  float4 a = *(const float4*)(XL + (size_t)node * DD + c0);
  a.x *= dv; a.y *= dv; a.z *= dv; a.w *= dv;
  const int beg = rowptr[node], end = rowptr[node + 1];
  int j = beg;
  for (; j + 1 < end; j += 2) {
    int s0 = csrc[j], s1 = csrc[j + 1];
    float n0 = cnrm[j], n1 = cnrm[j + 1];
    float4 u = *(const float4*)(XL + (size_t)s0 * DD + c0);
    float4 v = *(const float4*)(XL + (size_t)s1 * DD + c0);
    a.x = fmaf(u.x, n0, a.x); a.y = fmaf(u.y, n0, a.y);
    a.z = fmaf(u.z, n0, a.z); a.w = fmaf(u.w, n0, a.w);
    a.x = fmaf(v.x, n1, a.x); a.y = fmaf(v.y, n1, a.y);
    a.z = fmaf(v.z, n1, a.z); a.w = fmaf(v.w, n1, a.w);
  }
  if (j < end) {
    int s0 = csrc[j];
    float n0 = cnrm[j];
    float4 u = *(const float4*)(XL + (size_t)s0 * DD + c0);
    a.x = fmaf(u.x, n0, a.x); a.y = fmaf(u.y, n0, a.y);
    a.z = fmaf(u.z, n0, a.z); a.w = fmaf(u.w, n0, a.w);
  }
  float4 b = *(const float4*)(bg + c0);
  float* dst = ACC + (size_t)node * DD + c0;
  float4 c = *(const float4*)dst;
  c.x += a.x + b.x; c.y += a.y + b.y; c.z += a.z + b.z; c.w += a.w + b.w;
  *(float4*)dst = c;
}

// =====================================================================
// BatchNorm stats + finalize (BN + exact GELU)
// =====================================================================
__global__ __launch_bounds__(128) void k_colstats(const float* __restrict__ ACC,
                                                  float* __restrict__ cs,
                                                  float* __restrict__ csq) {
  const int col = blockIdx.y * 128 + threadIdx.x;
  const int r0 = blockIdx.x * 64;
  float s = 0.f, q = 0.f;
  for (int r = 0; r < 64; ++r) {
    float v = ACC[(size_t)(r0 + r) * DD + col];
    s += v;
    q = fmaf(v, v, q);
  }
  atomicAdd(cs + col, s);
  atomicAdd(csq + col, q);
}

__global__ __launch_bounds__(256) void k_finalize(const float* __restrict__ ACC,
                                                  const float* __restrict__ cs,
                                                  const float* __restrict__ csq,
                                                  const float* __restrict__ gamma,
                                                  const float* __restrict__ beta,
                                                  float* __restrict__ out) {
  const size_t i4 = (size_t)blockIdx.x * 256 + threadIdx.x;
  const int c = (int)(i4 & 127) << 2;
  float4 a = *(const float4*)(ACC + i4 * 4);
  float4 sv = *(const float4*)(cs + c);
  float4 qv = *(const float4*)(csq + c);
  float4 gv = *(const float4*)(gamma + c);
  float4 bv = *(const float4*)(beta + c);
  const float inv_n = 1.0f / (float)NNODE;
  float r[4];
  float av[4] = {a.x, a.y, a.z, a.w};
  float sa[4] = {sv.x, sv.y, sv.z, sv.w};
  float qa[4] = {qv.x, qv.y, qv.z, qv.w};
  float ga[4] = {gv.x, gv.y, gv.z, gv.w};
  float ba[4] = {bv.x, bv.y, bv.z, bv.w};
#pragma unroll
  for (int k = 0; k < 4; ++k) {
    float mu = sa[k] * inv_n;
    float var = qa[k] * inv_n - mu * mu;
    float g = (av[k] - mu) * rsqrtf(var + BNEPS) * ga[k] + ba[k];
    r[k] = 0.5f * g * (1.0f + erff(g * 0.70710678118654752f));
  }
  *(float4*)(out + i4 * 4) = make_float4(r[0], r[1], r[2], r[3]);
}

// =====================================================================
extern "C" void kernel_launch(void* const* d_in, const int* in_sizes, int n_in,
                              void* d_out, int out_size, void* d_ws, size_t ws_size,
                              hipStream_t stream) {
  const float* x   = (const float*)d_in[0];
  const int*   ei  = (const int*)d_in[1];
  const float* w   = (const float*)d_in[2];
  const float* Wq  = (const float*)d_in[4];
  const float* bq  = (const float*)d_in[5];
  const float* Wk  = (const float*)d_in[6];
  const float* bk  = (const float*)d_in[7];
  const float* Wv  = (const float*)d_in[8];
  const float* bv  = (const float*)d_in[9];
  const float* Wsk = (const float*)d_in[10];
  const float* bs  = (const float*)d_in[11];
  const float* Wg  = (const float*)d_in[12];
  const float* bg  = (const float*)d_in[13];
  const float* gam = (const float*)d_in[14];
  const float* bet = (const float*)d_in[15];

  float* wsf = (float*)d_ws;
  float* Qb   = wsf + OFF_Q;
  float* Kb   = wsf + OFF_K;
  float* Vb   = wsf + OFF_V;
  float* XL   = wsf + OFF_XL;
  float* ACC  = wsf + OFF_ACC;
  float* DEG  = wsf + OFF_DEG;
  float* CS   = wsf + OFF_CS;
  float* CSQ  = wsf + OFF_CSQ;
  int*   CNT  = (int*)(wsf + OFF_CNT);
  int*   CUR  = (int*)(wsf + OFF_CUR);
  float* DINV = wsf + OFF_DINV;
  int*   RP   = (int*)(wsf + OFF_RP);
  int*   CSRC = (int*)(wsf + OFF_CSRC);
  float* CNRM = wsf + OFF_CNRM;
  ushort* AP  = (ushort*)(wsf + OFF_AP);
  ushort* WP  = (ushort*)(wsf + OFF_WP);

  hipMemsetAsync(wsf + OFF_DEG, 0, (size_t)NZERO * 4, stream);

  if (ws_size >= WS_NEED_MFMA) {
    // split-bf16 conversions + 5 MFMA GEMMs (K3-interleaved)
    k_cvtA<<<4096, 256, 0, stream>>>(x, AP);
    k_cvtW<<<dim3(8, 8, 5), 256, 0, stream>>>(Wq, Wk, Wv, Wsk, Wg, WP);
    dim3 gg(DD / 128, NNODE / 128);  // (4, 128)
    const size_t WSTRIDE = (size_t)DD * K3;
    k_gemm_mfma<<<gg, 256, 0, stream>>>(AP, WP + 0 * WSTRIDE, bq, Qb);
    k_gemm_mfma<<<gg, 256, 0, stream>>>(AP, WP + 1 * WSTRIDE, bk, Kb);
    k_gemm_mfma<<<gg, 256, 0, stream>>>(AP, WP + 2 * WSTRIDE, bv, Vb);
    k_gemm_mfma<<<gg, 256, 0, stream>>>(AP, WP + 3 * WSTRIDE, bs, ACC);
    k_gemm_mfma<<<gg, 256, 0, stream>>>(AP, WP + 4 * WSTRIDE, nullptr, XL);
  } else {
    // fp32 fallback (R1-proven)
    dim3 gg(DD / 64, NNODE / 64);  // (8, 256)
    k_gemm<<<gg, 256, 0, stream>>>(x, Wq, bq, Qb);
    k_gemm<<<gg, 256, 0, stream>>>(x, Wk, bk, Kb);
    k_gemm<<<gg, 256, 0, stream>>>(x, Wv, bv, Vb);
    k_gemm<<<gg, 256, 0, stream>>>(x, Wsk, bs, ACC);
    k_gemm<<<gg, 256, 0, stream>>>(x, Wg, nullptr, XL);
  }

  k_degcnt<<<NE / 256, 256, 0, stream>>>(ei, w, DEG, CNT);
  k_dinv<<<NNODE / 256, 256, 0, stream>>>(DEG, DINV);
  k_scan<<<1, 256, 0, stream>>>(CNT, RP);
  k_fill<<<NE / 256, 256, 0, stream>>>(ei, w, DINV, RP, CUR, CSRC, CNRM);

  k_attn<<<dim3(NB * HH, NN / 64), 256, 0, stream>>>(Qb, Kb, Vb, ACC);
  k_aggregate<<<NNODE / 2, 256, 0, stream>>>(RP, CSRC, CNRM, XL, DINV, bg, ACC);

  k_colstats<<<dim3(NNODE / 64, DD / 128), 128, 0, stream>>>(ACC, CS, CSQ);
  k_finalize<<<(NNODE * DD / 4) / 256, 256, 0, stream>>>(ACC, CS, CSQ, gam, bet, (float*)d_out);
}

// Round 6
// 608.476 us; speedup vs baseline: 1.5784x; 1.1056x over previous
//
#include <hip/hip_runtime.h>
#include <math.h>

// Problem constants
#define NB    64
#define NN    256
#define NNODE 16384      // NB*NN
#define DD    512
#define HH    8
#define HDIM  64
#define NE    262144
#define BNEPS 1e-5f
#define K3    1536       // split-bf16 interleaved K (3 * 512)
#define KSTEPS 48        // K3 / 32

// ---------------- workspace layout (4-byte units) ----------------
// Q2/K2/V2: bf16 [hi|lo] pairs [16384][1024] ushorts = 33.5MB each (same size
// as the old fp32 buffers, same offsets).
#define OFF_Q    0ull
#define OFF_K    8388608ull
#define OFF_V    16777216ull
#define OFF_XL   25165824ull
#define OFF_ACC  33554432ull
#define OFF_DEG  41943040ull
#define OFF_CS   (OFF_DEG + NNODE)
#define OFF_CSQ  (OFF_CS + DD)
#define OFF_CNT  (OFF_CSQ + DD)
#define OFF_CUR  (OFF_CNT + NNODE)
#define NZERO    (NNODE + DD + DD + NNODE + NNODE)
#define OFF_DINV (OFF_CUR + NNODE)
#define OFF_RP   (OFF_DINV + NNODE)
#define OFF_CSRC (OFF_RP + NNODE + 1)
#define OFF_CNRM (OFF_CSRC + NE)
#define OFF_AP   42550280ull                  // bf16 A' [16384][1536]
#define OFF_WP   (OFF_AP + 12582912ull)       // bf16 W'  [5][512][1536]

typedef __attribute__((ext_vector_type(8))) short bf16x8;
typedef __attribute__((ext_vector_type(4))) float f32x4;

__device__ __forceinline__ ushort bf16rn(float v) {
  uint u = __float_as_uint(v);
  u += 0x7FFF + ((u >> 16) & 1);
  return (ushort)(u >> 16);
}

// =====================================================================
// fp32 -> split-bf16 conversions (GEMM inputs)
// A'[m][3k+0]=hi(x[m][k]) [3k+1]=lo [3k+2]=hi
// =====================================================================
__global__ __launch_bounds__(256) void k_cvtA(const float* __restrict__ x,
                                              ushort* __restrict__ Ap) {
  const size_t t = (size_t)blockIdx.x * 256 + threadIdx.x;
  const int row = (int)(t >> 6);
  const int kc = (int)(t & 63);
  const float* src = x + (size_t)row * DD + kc * 8;
  float4 v0 = *(const float4*)(src);
  float4 v1 = *(const float4*)(src + 4);
  float vv[8] = {v0.x, v0.y, v0.z, v0.w, v1.x, v1.y, v1.z, v1.w};
  ushort o[24];
#pragma unroll
  for (int j = 0; j < 8; ++j) {
    float v = vv[j];
    ushort h = bf16rn(v);
    float hf = __uint_as_float((uint)h << 16);
    ushort l = bf16rn(v - hf);
    o[3 * j] = h; o[3 * j + 1] = l; o[3 * j + 2] = h;
  }
  uint uu[12];
#pragma unroll
  for (int i = 0; i < 12; ++i) uu[i] = (uint)o[2 * i] | ((uint)o[2 * i + 1] << 16);
  uint4* dst = (uint4*)(Ap + (size_t)row * K3 + kc * 24);
  dst[0] = make_uint4(uu[0], uu[1], uu[2], uu[3]);
  dst[1] = make_uint4(uu[4], uu[5], uu[6], uu[7]);
  dst[2] = make_uint4(uu[8], uu[9], uu[10], uu[11]);
}

// W[k][n] -> W'[n][3k+0]=hi [3k+1]=hi [3k+2]=lo   (transposed, per weight z)
__global__ __launch_bounds__(256) void k_cvtW(const float* __restrict__ W0,
                                              const float* __restrict__ W1,
                                              const float* __restrict__ W2,
                                              const float* __restrict__ W3,
                                              const float* __restrict__ W4,
                                              ushort* __restrict__ Wp) {
  __shared__ float Wl[64][65];
  const float* const Wt[5] = {W0, W1, W2, W3, W4};
  const float* W = Wt[blockIdx.z];
  ushort* dst_base = Wp + (size_t)blockIdx.z * (DD * K3);
  const int k0 = blockIdx.x * 64, n0 = blockIdx.y * 64;
  const int tid = threadIdx.x;
#pragma unroll
  for (int i = 0; i < 4; ++i) {
    int r = (tid >> 4) + i * 16;
    int c4 = (tid & 15) * 4;
    float4 v = *(const float4*)(W + (size_t)(k0 + r) * DD + n0 + c4);
    Wl[r][c4 + 0] = v.x; Wl[r][c4 + 1] = v.y; Wl[r][c4 + 2] = v.z; Wl[r][c4 + 3] = v.w;
  }
  __syncthreads();
  const int nl = tid >> 2;
  const int kc = (tid & 3) * 16;
  ushort o[48];
#pragma unroll
  for (int j = 0; j < 16; ++j) {
    float v = Wl[kc + j][nl];
    ushort h = bf16rn(v);
    float hf = __uint_as_float((uint)h << 16);
    ushort l = bf16rn(v - hf);
    o[3 * j] = h; o[3 * j + 1] = h; o[3 * j + 2] = l;
  }
  uint uu[24];
#pragma unroll
  for (int i = 0; i < 24; ++i) uu[i] = (uint)o[2 * i] | ((uint)o[2 * i + 1] << 16);
  uint4* dst = (uint4*)(dst_base + (size_t)(n0 + nl) * K3 + (size_t)(k0 + kc) * 3);
#pragma unroll
  for (int i = 0; i < 6; ++i)
    dst[i] = make_uint4(uu[4 * i], uu[4 * i + 1], uu[4 * i + 2], uu[4 * i + 3]);
}

// =====================================================================
// MFMA GEMM: out[16384x512] = A'[16384xK3] @ W'[512xK3]^T (+bias)
// MODE 0: fp32 C. MODE 1: bf16 [hi|lo] head-pair layout [row][h*128+hd(+64)],
//         scaled (Q uses 0.125).
// =====================================================================
template <int MODE>
__global__ __launch_bounds__(256) void k_gemm_mfma(const ushort* __restrict__ Ap,
                                                   const ushort* __restrict__ Bp,
                                                   const float* __restrict__ bias,
                                                   float scale,
                                                   void* __restrict__ Cout) {
  __shared__ ushort Asm[2][128][32];
  __shared__ ushort Bsm[2][128][32];
  const int tid = threadIdx.x;
  const int lane = tid & 63;
  const int wv = tid >> 6;
  const int row0 = blockIdx.y * 128;
  const int col0 = blockIdx.x * 128;
  const int srow = lane >> 2;
  const int sk8 = (lane & 3) * 8;
  const int lane16 = lane & 15;
  const int lq = lane >> 4;
  const int wm = (wv >> 1) * 64;
  const int wn = (wv & 1) * 64;

#define STAGE(buf, t)                                                                   \
  do {                                                                                  \
    const int k0s = (t) * 32;                                                           \
    _Pragma("unroll") for (int c = wv; c < 8; c += 4) {                                 \
      const ushort* ga = Ap + (size_t)(row0 + c * 16 + srow) * K3 + k0s + sk8;          \
      __builtin_amdgcn_global_load_lds(                                                 \
          (const __attribute__((address_space(1))) void*)ga,                            \
          (__attribute__((address_space(3))) void*)&Asm[buf][c * 16][0], 16, 0, 0);     \
      const ushort* gb = Bp + (size_t)(col0 + c * 16 + srow) * K3 + k0s + sk8;          \
      __builtin_amdgcn_global_load_lds(                                                 \
          (const __attribute__((address_space(1))) void*)gb,                            \
          (__attribute__((address_space(3))) void*)&Bsm[buf][c * 16][0], 16, 0, 0);     \
    }                                                                                   \
  } while (0)

  f32x4 acc[4][4];
#pragma unroll
  for (int m = 0; m < 4; ++m)
#pragma unroll
    for (int n = 0; n < 4; ++n) acc[m][n] = (f32x4){0.f, 0.f, 0.f, 0.f};

  STAGE(0, 0);
  int cur = 0;
  for (int t = 0; t < KSTEPS; ++t) {
    __syncthreads();
    if (t + 1 < KSTEPS) STAGE(cur ^ 1, t + 1);
    bf16x8 av[4], bv[4];
#pragma unroll
    for (int m = 0; m < 4; ++m)
      av[m] = *(const bf16x8*)&Asm[cur][wm + m * 16 + lane16][lq * 8];
#pragma unroll
    for (int n = 0; n < 4; ++n)
      bv[n] = *(const bf16x8*)&Bsm[cur][wn + n * 16 + lane16][lq * 8];
#pragma unroll
    for (int m = 0; m < 4; ++m)
#pragma unroll
      for (int n = 0; n < 4; ++n)
        acc[m][n] = __builtin_amdgcn_mfma_f32_16x16x32_bf16(av[m], bv[n], acc[m][n], 0, 0, 0);
    cur ^= 1;
  }
#pragma unroll
  for (int n = 0; n < 4; ++n) {
    const int col = col0 + wn + n * 16 + lane16;
    const float bb = bias ? bias[col] : 0.0f;
    if (MODE == 0) {
      float* C = (float*)Cout;
#pragma unroll
      for (int m = 0; m < 4; ++m) {
        const int row = row0 + wm + m * 16 + lq * 4;
#pragma unroll
        for (int r = 0; r < 4; ++r)
          C[(size_t)(row + r) * DD + col] = acc[m][n][r] + bb;
      }
    } else {
      ushort* C2 = (ushort*)Cout;
      const int hcol = (col >> 6) * 128 + (col & 63);
#pragma unroll
      for (int m = 0; m < 4; ++m) {
        const int row = row0 + wm + m * 16 + lq * 4;
#pragma unroll
        for (int r = 0; r < 4; ++r) {
          float val = (acc[m][n][r] + bb) * scale;
          ushort hi = bf16rn(val);
          float hf = __uint_as_float((uint)hi << 16);
          ushort lo = bf16rn(val - hf);
          C2[(size_t)(row + r) * 1024 + hcol] = hi;
          C2[(size_t)(row + r) * 1024 + hcol + 64] = lo;
        }
      }
    }
  }
#undef STAGE
}

// =====================================================================
// MFMA flash attention. Grid (512 bh, 2 qb), 256 thr = 4 waves x 32 q.
// Swapped QK^T (A=K, B=Q) -> P forms in-register for PV.
// Q: [hi|hi|lo] segments (3-term w/ K [hi|lo|hi]); V: [hi|lo] pairs, P dup'd.
// ACC[q][h*64+d] += softmax(QK^T) @ V  (Q pre-scaled 1/8 in GEMM epilogue)
// =====================================================================
__global__ __launch_bounds__(256) void k_attn_mfma(const ushort* __restrict__ Q2,
                                                   const ushort* __restrict__ K2,
                                                   const ushort* __restrict__ V2,
                                                   float* __restrict__ ACC) {
  __shared__ ushort KL[64][136];  // [key][hi(64)|lo(64)] pairs, pad->conflict-free
  __shared__ ushort VT[64][138];  // [d][(vhi,vlo) per key], pad 138
  const int tid = threadIdx.x;
  const int lane = tid & 63;
  const int wv = tid >> 6;
  const int l16 = lane & 15;
  const int lq = lane >> 4;
  const int bh = blockIdx.x;
  const int qb = blockIdx.y;
  const int b = bh >> 3, h = bh & 7;
  const int hoff = h * 128;
  const int node0 = b * NN;
  const int q0w = qb * 128 + wv * 32;

  // Q B-fragments in registers: qf[n(q-group)][s(kstep of 192)]
  bf16x8 qf[2][6];
#pragma unroll
  for (int n = 0; n < 2; ++n) {
    const ushort* qrow = Q2 + (size_t)(node0 + q0w + n * 16 + l16) * 1024 + hoff;
#pragma unroll
    for (int s = 0; s < 6; ++s) {
      const int c = s * 4 + lq;                 // chunk 0..23 of [hi|hi|lo]
      const int phys = (c < 8) ? c : (c - 8);   // ->[hi(0..7)|lo(8..15)]
      qf[n][s] = *(const bf16x8*)(qrow + phys * 8);
    }
  }

  const int skey = tid >> 2;  // staging: key 0..63
  const int sq = tid & 3;
  const ushort* krow_base = K2 + (size_t)(node0 + skey) * 1024 + hoff;
  const ushort* vrow_base = V2 + (size_t)(node0 + skey) * 1024 + hoff;

  uint4 kreg[4], vh[2], vl[2];
#define LOADKV(kt)                                               \
  do {                                                           \
    const ushort* kr = krow_base + (size_t)(kt) * 64 * 1024;     \
    kreg[0] = *(const uint4*)(kr + (sq * 4 + 0) * 8);            \
    kreg[1] = *(const uint4*)(kr + (sq * 4 + 1) * 8);            \
    kreg[2] = *(const uint4*)(kr + (sq * 4 + 2) * 8);            \
    kreg[3] = *(const uint4*)(kr + (sq * 4 + 3) * 8);            \
    const ushort* vr = vrow_base + (size_t)(kt) * 64 * 1024;     \
    vh[0] = *(const uint4*)(vr + sq * 16);                       \
    vh[1] = *(const uint4*)(vr + sq * 16 + 8);                   \
    vl[0] = *(const uint4*)(vr + 64 + sq * 16);                  \
    vl[1] = *(const uint4*)(vr + 64 + sq * 16 + 8);              \
  } while (0)

  f32x4 o[2][4];
#pragma unroll
  for (int a = 0; a < 2; ++a)
#pragma unroll
    for (int c2 = 0; c2 < 4; ++c2) o[a][c2] = (f32x4){0.f, 0.f, 0.f, 0.f};
  float mrun[2] = {-INFINITY, -INFINITY};
  float lrun[2] = {0.f, 0.f};

  LOADKV(0);
  for (int kt = 0; kt < 4; ++kt) {
    // regs -> LDS (prev tile reads completed at loop-end barrier)
    *(uint4*)(&KL[skey][(sq * 4 + 0) * 8]) = kreg[0];
    *(uint4*)(&KL[skey][(sq * 4 + 1) * 8]) = kreg[1];
    *(uint4*)(&KL[skey][(sq * 4 + 2) * 8]) = kreg[2];
    *(uint4*)(&KL[skey][(sq * 4 + 3) * 8]) = kreg[3];
    {
      const ushort* hh = (const ushort*)vh;
      const ushort* llp = (const ushort*)vl;
#pragma unroll
      for (int j = 0; j < 16; ++j) {
        uint v = (uint)hh[j] | ((uint)llp[j] << 16);
        *((uint*)(&VT[sq * 16 + j][0]) + skey) = v;
      }
    }
    __syncthreads();
    if (kt < 3) LOADKV(kt + 1);  // T14: prefetch under compute

    // ---- QK^T (S^T): A=K [hi|lo|hi], B=Q regs ----
    f32x4 sa[4][2];
#pragma unroll
    for (int m = 0; m < 4; ++m) {
      sa[m][0] = (f32x4){0.f, 0.f, 0.f, 0.f};
      sa[m][1] = (f32x4){0.f, 0.f, 0.f, 0.f};
    }
#pragma unroll
    for (int s = 0; s < 6; ++s) {
      const int c = s * 4 + lq;
      const int phys = (c < 16) ? c : (c - 16);
      bf16x8 ak[4];
#pragma unroll
      for (int m = 0; m < 4; ++m)
        ak[m] = *(const bf16x8*)(&KL[m * 16 + l16][phys * 8]);
#pragma unroll
      for (int m = 0; m < 4; ++m) {
        sa[m][0] = __builtin_amdgcn_mfma_f32_16x16x32_bf16(ak[m], qf[0][s], sa[m][0], 0, 0, 0);
        sa[m][1] = __builtin_amdgcn_mfma_f32_16x16x32_bf16(ak[m], qf[1][s], sa[m][1], 0, 0, 0);
      }
    }

    // ---- online softmax (per lane: q = n*16+l16, keys = m*16+lq*4+r) ----
    bf16x8 pa[4][2];
#pragma unroll
    for (int n = 0; n < 2; ++n) {
      float mt = sa[0][n][0];
#pragma unroll
      for (int m = 0; m < 4; ++m)
#pragma unroll
        for (int r = 0; r < 4; ++r) mt = fmaxf(mt, sa[m][n][r]);
      mt = fmaxf(mt, __shfl_xor(mt, 16, 64));
      mt = fmaxf(mt, __shfl_xor(mt, 32, 64));
      const float mn = fmaxf(mrun[n], mt);
      const float sc = __expf(mrun[n] - mn);
      mrun[n] = mn;
      float rs = 0.f;
#pragma unroll
      for (int m = 0; m < 4; ++m)
#pragma unroll
        for (int r = 0; r < 4; ++r) {
          float p = __expf(sa[m][n][r] - mn);
          sa[m][n][r] = p;
          rs += p;
        }
      rs += __shfl_xor(rs, 16, 64);
      rs += __shfl_xor(rs, 32, 64);
      lrun[n] = lrun[n] * sc + rs;
      // rescale o rows of q-group n: o element r sits at q = n*16+lq*4+r
#pragma unroll
      for (int r = 0; r < 4; ++r) {
        const float scO = __shfl(sc, lq * 4 + r, 64);
#pragma unroll
        for (int np = 0; np < 4; ++np) o[n][np][r] *= scO;
      }
      // pack PV A-frags: pa[s4][n] = dup pairs of exp'd scores (keys s4*16+lq*4+r)
#pragma unroll
      for (int m = 0; m < 4; ++m) {
        ushort p0 = bf16rn(sa[m][n][0]);
        ushort p1 = bf16rn(sa[m][n][1]);
        ushort p2 = bf16rn(sa[m][n][2]);
        ushort p3 = bf16rn(sa[m][n][3]);
        bf16x8 tpk;
        tpk[0] = (short)p0; tpk[1] = (short)p0;
        tpk[2] = (short)p1; tpk[3] = (short)p1;
        tpk[4] = (short)p2; tpk[5] = (short)p2;
        tpk[6] = (short)p3; tpk[7] = (short)p3;
        pa[m][n] = tpk;
      }
    }

    // ---- PV: A=P(dup), B=VT (vhi,vlo pairs) ----
#pragma unroll
    for (int s4 = 0; s4 < 4; ++s4) {
#pragma unroll
      for (int np = 0; np < 4; ++np) {
        bf16x8 bvv = *(const bf16x8*)(&VT[np * 16 + l16][s4 * 32 + lq * 8]);
        o[0][np] = __builtin_amdgcn_mfma_f32_16x16x32_bf16(pa[s4][0], bvv, o[0][np], 0, 0, 0);
        o[1][np] = __builtin_amdgcn_mfma_f32_16x16x32_bf16(pa[s4][1], bvv, o[1][np], 0, 0, 0);
      }
    }
    __syncthreads();  // LDS reads done; next iter overwrites
  }

  // epilogue: O rows q = q0w + mp*16 + lq*4 + r; cols d = np*16 + l16
#pragma unroll
  for (int mp = 0; mp < 2; ++mp) {
    const float linv_l = 1.0f / lrun[mp];
#pragma unroll
    for (int r = 0; r < 4; ++r) {
      const float linv = __shfl(linv_l, lq * 4 + r, 64);
      float* dst = ACC + (size_t)(node0 + q0w + mp * 16 + lq * 4 + r) * DD + h * 64 + l16;
#pragma unroll
      for (int np = 0; np < 4; ++np)
        dst[np * 16] += o[mp][np][r] * linv;
    }
  }
#undef LOADKV
}

// =====================================================================
// GCN plumbing
// =====================================================================
__global__ __launch_bounds__(256) void k_degcnt(const int* __restrict__ ei,
                                                const float* __restrict__ w,
                                                float* __restrict__ deg,
                                                int* __restrict__ cnt) {
  int e = blockIdx.x * 256 + threadIdx.x;
  if (e < NE) {
    int d = ei[NE + e];
    atomicAdd(deg + d, w[e]);
    atomicAdd(cnt + d, 1);
  }
}

__global__ __launch_bounds__(256) void k_dinv(const float* __restrict__ deg,
                                              float* __restrict__ dinv) {
  int i = blockIdx.x * 256 + threadIdx.x;
  if (i < NNODE) dinv[i] = rsqrtf(deg[i] + 1.0f);
}

__global__ __launch_bounds__(256) void k_scan(const int* __restrict__ cnt,
                                              int* __restrict__ rowptr) {
  __shared__ int part[256];
  __shared__ int excl[257];
  const int t = threadIdx.x;
  const int base = t * 64;
  int s = 0;
  for (int j = 0; j < 64; ++j) s += cnt[base + j];
  part[t] = s;
  __syncthreads();
  if (t == 0) {
    int run = 0;
    for (int i = 0; i < 256; ++i) { excl[i] = run; run += part[i]; }
    excl[256] = run;
  }
  __syncthreads();
  int run = excl[t];
  for (int j = 0; j < 64; ++j) { rowptr[base + j] = run; run += cnt[base + j]; }
  if (t == 255) rowptr[NNODE] = excl[256];
}

__global__ __launch_bounds__(256) void k_fill(const int* __restrict__ ei,
                                              const float* __restrict__ w,
                                              const float* __restrict__ dinv,
                                              const int* __restrict__ rowptr,
                                              int* __restrict__ cursor,
                                              int* __restrict__ csrc,
                                              float* __restrict__ cnrm) {
  int e = blockIdx.x * 256 + threadIdx.x;
  if (e >= NE) return;
  int s = ei[e], d = ei[NE + e];
  int p = rowptr[d] + atomicAdd(cursor + d, 1);
  csrc[p] = s;
  cnrm[p] = dinv[s] * w[e] * dinv[d];
}

__global__ __launch_bounds__(256) void k_aggregate(const int* __restrict__ rowptr,
                                                   const int* __restrict__ csrc,
                                                   const float* __restrict__ cnrm,
                                                   const float* __restrict__ XL,
                                                   const float* __restrict__ dinv,
                                                   const float* __restrict__ bg,
                                                   float* __restrict__ ACC) {
  const int node = blockIdx.x * 2 + (threadIdx.x >> 7);
  const int c0 = (threadIdx.x & 127) << 2;
  float dv = dinv[node];
  dv *= dv;
  float4 a = *(const float4*)(XL + (size_t)node * DD + c0);
  a.x *= dv; a.y *= dv; a.z *= dv; a.w *= dv;
  const int beg = rowptr[node], end = rowptr[node + 1];
  int j = beg;
  for (; j + 1 < end; j += 2) {
    int s0 = csrc[j], s1 = csrc[j + 1];
    float n0 = cnrm[j], n1 = cnrm[j + 1];
    float4 u = *(const float4*)(XL + (size_t)s0 * DD + c0);
    float4 v = *(const float4*)(XL + (size_t)s1 * DD + c0);
    a.x = fmaf(u.x, n0, a.x); a.y = fmaf(u.y, n0, a.y);
    a.z = fmaf(u.z, n0, a.z); a.w = fmaf(u.w, n0, a.w);
    a.x = fmaf(v.x, n1, a.x); a.y = fmaf(v.y, n1, a.y);
    a.z = fmaf(v.z, n1, a.z); a.w = fmaf(v.w, n1, a.w);
  }
  if (j < end) {
    int s0 = csrc[j];
    float n0 = cnrm[j];
    float4 u = *(const float4*)(XL + (size_t)s0 * DD + c0);
    a.x = fmaf(u.x, n0, a.x); a.y = fmaf(u.y, n0, a.y);
    a.z = fmaf(u.z, n0, a.z); a.w = fmaf(u.w, n0, a.w);
  }
  float4 b = *(const float4*)(bg + c0);
  float* dst = ACC + (size_t)node * DD + c0;
  float4 c = *(const float4*)dst;
  c.x += a.x + b.x; c.y += a.y + b.y; c.z += a.z + b.z; c.w += a.w + b.w;
  *(float4*)dst = c;
}

// =====================================================================
// BatchNorm stats + finalize (BN + exact GELU)
// =====================================================================
__global__ __launch_bounds__(128) void k_colstats(const float* __restrict__ ACC,
                                                  float* __restrict__ cs,
                                                  float* __restrict__ csq) {
  const int col = blockIdx.y * 128 + threadIdx.x;
  const int r0 = blockIdx.x * 64;
  float s = 0.f, q = 0.f;
  for (int r = 0; r < 64; ++r) {
    float v = ACC[(size_t)(r0 + r) * DD + col];
    s += v;
    q = fmaf(v, v, q);
  }
  atomicAdd(cs + col, s);
  atomicAdd(csq + col, q);
}

__global__ __launch_bounds__(256) void k_finalize(const float* __restrict__ ACC,
                                                  const float* __restrict__ cs,
                                                  const float* __restrict__ csq,
                                                  const float* __restrict__ gamma,
                                                  const float* __restrict__ beta,
                                                  float* __restrict__ out) {
  const size_t i4 = (size_t)blockIdx.x * 256 + threadIdx.x;
  const int c = (int)(i4 & 127) << 2;
  float4 a = *(const float4*)(ACC + i4 * 4);
  float4 sv = *(const float4*)(cs + c);
  float4 qv = *(const float4*)(csq + c);
  float4 gv = *(const float4*)(gamma + c);
  float4 bv = *(const float4*)(beta + c);
  const float inv_n = 1.0f / (float)NNODE;
  float r[4];
  float av[4] = {a.x, a.y, a.z, a.w};
  float sa[4] = {sv.x, sv.y, sv.z, sv.w};
  float qa[4] = {qv.x, qv.y, qv.z, qv.w};
  float ga[4] = {gv.x, gv.y, gv.z, gv.w};
  float ba[4] = {bv.x, bv.y, bv.z, bv.w};
#pragma unroll
  for (int k = 0; k < 4; ++k) {
    float mu = sa[k] * inv_n;
    float var = qa[k] * inv_n - mu * mu;
    float g = (av[k] - mu) * rsqrtf(var + BNEPS) * ga[k] + ba[k];
    r[k] = 0.5f * g * (1.0f + erff(g * 0.70710678118654752f));
  }
  *(float4*)(out + i4 * 4) = make_float4(r[0], r[1], r[2], r[3]);
}

// =====================================================================
extern "C" void kernel_launch(void* const* d_in, const int* in_sizes, int n_in,
                              void* d_out, int out_size, void* d_ws, size_t ws_size,
                              hipStream_t stream) {
  const float* x   = (const float*)d_in[0];
  const int*   ei  = (const int*)d_in[1];
  const float* w   = (const float*)d_in[2];
  const float* Wq  = (const float*)d_in[4];
  const float* bq  = (const float*)d_in[5];
  const float* Wk  = (const float*)d_in[6];
  const float* bk  = (const float*)d_in[7];
  const float* Wv  = (const float*)d_in[8];
  const float* bv  = (const float*)d_in[9];
  const float* Wsk = (const float*)d_in[10];
  const float* bs  = (const float*)d_in[11];
  const float* Wg  = (const float*)d_in[12];
  const float* bg  = (const float*)d_in[13];
  const float* gam = (const float*)d_in[14];
  const float* bet = (const float*)d_in[15];

  float* wsf = (float*)d_ws;
  ushort* Q2  = (ushort*)(wsf + OFF_Q);
  ushort* K2b = (ushort*)(wsf + OFF_K);
  ushort* V2b = (ushort*)(wsf + OFF_V);
  float* XL   = wsf + OFF_XL;
  float* ACC  = wsf + OFF_ACC;
  float* DEG  = wsf + OFF_DEG;
  float* CS   = wsf + OFF_CS;
  float* CSQ  = wsf + OFF_CSQ;
  int*   CNT  = (int*)(wsf + OFF_CNT);
  int*   CUR  = (int*)(wsf + OFF_CUR);
  float* DINV = wsf + OFF_DINV;
  int*   RP   = (int*)(wsf + OFF_RP);
  int*   CSRC = (int*)(wsf + OFF_CSRC);
  float* CNRM = wsf + OFF_CNRM;
  ushort* AP  = (ushort*)(wsf + OFF_AP);
  ushort* WP  = (ushort*)(wsf + OFF_WP);

  hipMemsetAsync(wsf + OFF_DEG, 0, (size_t)NZERO * 4, stream);

  // split-bf16 conversions (GEMM inputs)
  k_cvtA<<<4096, 256, 0, stream>>>(x, AP);
  k_cvtW<<<dim3(8, 8, 5), 256, 0, stream>>>(Wq, Wk, Wv, Wsk, Wg, WP);

  // 5 MFMA GEMMs; Q/K/V emit bf16 [hi|lo] pairs (Q pre-scaled 1/8)
  dim3 gg(DD / 128, NNODE / 128);  // (4, 128)
  const size_t WSTRIDE = (size_t)DD * K3;
  k_gemm_mfma<1><<<gg, 256, 0, stream>>>(AP, WP + 0 * WSTRIDE, bq, 0.125f, Q2);
  k_gemm_mfma<1><<<gg, 256, 0, stream>>>(AP, WP + 1 * WSTRIDE, bk, 1.0f, K2b);
  k_gemm_mfma<1><<<gg, 256, 0, stream>>>(AP, WP + 2 * WSTRIDE, bv, 1.0f, V2b);
  k_gemm_mfma<0><<<gg, 256, 0, stream>>>(AP, WP + 3 * WSTRIDE, bs, 1.0f, ACC);
  k_gemm_mfma<0><<<gg, 256, 0, stream>>>(AP, WP + 4 * WSTRIDE, nullptr, 1.0f, XL);

  k_degcnt<<<NE / 256, 256, 0, stream>>>(ei, w, DEG, CNT);
  k_dinv<<<NNODE / 256, 256, 0, stream>>>(DEG, DINV);
  k_scan<<<1, 256, 0, stream>>>(CNT, RP);
  k_fill<<<NE / 256, 256, 0, stream>>>(ei, w, DINV, RP, CUR, CSRC, CNRM);

  k_attn_mfma<<<dim3(NB * HH, 2), 256, 0, stream>>>(Q2, K2b, V2b, ACC);
  k_aggregate<<<NNODE / 2, 256, 0, stream>>>(RP, CSRC, CNRM, XL, DINV, bg, ACC);

  k_colstats<<<dim3(NNODE / 64, DD / 128), 128, 0, stream>>>(ACC, CS, CSQ);
  k_finalize<<<(NNODE * DD / 4) / 256, 256, 0, stream>>>(ACC, CS, CSQ, gam, bet, (float*)d_out);
}

// Round 8
// 562.889 us; speedup vs baseline: 1.7062x; 1.0810x over previous
//
#include <hip/hip_runtime.h>
#include <math.h>

// Problem constants
#define NB    64
#define NN    256
#define NNODE 16384      // NB*NN
#define DD    512
#define HH    8
#define HDIM  64
#define NE    262144
#define BNEPS 1e-5f
#define K3    1536       // split-bf16 interleaved K (3 * 512)
#define KSTEPS 48        // K3 / 32

// ---------------- workspace layout (4-byte units) ----------------
// Q2/K2/V2: bf16 [hi|lo] pairs [16384][1024] ushorts = 33.5MB each,
// contiguous from offset 0 (QKV base = ws).
#define OFF_Q    0ull
#define OFF_K    8388608ull
#define OFF_V    16777216ull
#define OFF_XL   25165824ull
#define OFF_ACC  33554432ull
#define OFF_DEG  41943040ull
#define OFF_CS   (OFF_DEG + NNODE)
#define OFF_CSQ  (OFF_CS + DD)
#define OFF_CNT  (OFF_CSQ + DD)
#define OFF_CUR  (OFF_CNT + NNODE)
#define NZERO    (NNODE + DD + DD + NNODE + NNODE)
#define OFF_DINV (OFF_CUR + NNODE)
#define OFF_RP   (OFF_DINV + NNODE)
#define OFF_CSRC (OFF_RP + NNODE + 1)
#define OFF_CNRM (OFF_CSRC + NE)
#define OFF_AP   42550280ull                  // bf16 A' [16384][1536]
#define OFF_WP   (OFF_AP + 12582912ull)       // bf16 W'  [5][512][1536] = [2560][1536]

typedef __attribute__((ext_vector_type(8))) short bf16x8;
typedef __attribute__((ext_vector_type(4))) float f32x4;

__device__ __forceinline__ ushort bf16rn(float v) {
  uint u = __float_as_uint(v);
  u += 0x7FFF + ((u >> 16) & 1);
  return (ushort)(u >> 16);
}

// =====================================================================
// fp32 -> split-bf16 conversions (GEMM inputs)
// A'[m][3k+0]=hi(x[m][k]) [3k+1]=lo [3k+2]=hi
// =====================================================================
__global__ __launch_bounds__(256) void k_cvtA(const float* __restrict__ x,
                                              ushort* __restrict__ Ap) {
  const size_t t = (size_t)blockIdx.x * 256 + threadIdx.x;
  const int row = (int)(t >> 6);
  const int kc = (int)(t & 63);
  const float* src = x + (size_t)row * DD + kc * 8;
  float4 v0 = *(const float4*)(src);
  float4 v1 = *(const float4*)(src + 4);
  float vv[8] = {v0.x, v0.y, v0.z, v0.w, v1.x, v1.y, v1.z, v1.w};
  ushort o[24];
#pragma unroll
  for (int j = 0; j < 8; ++j) {
    float v = vv[j];
    ushort h = bf16rn(v);
    float hf = __uint_as_float((uint)h << 16);
    ushort l = bf16rn(v - hf);
    o[3 * j] = h; o[3 * j + 1] = l; o[3 * j + 2] = h;
  }
  uint uu[12];
#pragma unroll
  for (int i = 0; i < 12; ++i) uu[i] = (uint)o[2 * i] | ((uint)o[2 * i + 1] << 16);
  uint4* dst = (uint4*)(Ap + (size_t)row * K3 + kc * 24);
  dst[0] = make_uint4(uu[0], uu[1], uu[2], uu[3]);
  dst[1] = make_uint4(uu[4], uu[5], uu[6], uu[7]);
  dst[2] = make_uint4(uu[8], uu[9], uu[10], uu[11]);
}

// W[k][n] -> W'[n][3k+0]=hi [3k+1]=hi [3k+2]=lo   (transposed, per weight z)
__global__ __launch_bounds__(256) void k_cvtW(const float* __restrict__ W0,
                                              const float* __restrict__ W1,
                                              const float* __restrict__ W2,
                                              const float* __restrict__ W3,
                                              const float* __restrict__ W4,
                                              ushort* __restrict__ Wp) {
  __shared__ float Wl[64][65];
  const float* const Wt[5] = {W0, W1, W2, W3, W4};
  const float* W = Wt[blockIdx.z];
  ushort* dst_base = Wp + (size_t)blockIdx.z * (DD * K3);
  const int k0 = blockIdx.x * 64, n0 = blockIdx.y * 64;
  const int tid = threadIdx.x;
#pragma unroll
  for (int i = 0; i < 4; ++i) {
    int r = (tid >> 4) + i * 16;
    int c4 = (tid & 15) * 4;
    float4 v = *(const float4*)(W + (size_t)(k0 + r) * DD + n0 + c4);
    Wl[r][c4 + 0] = v.x; Wl[r][c4 + 1] = v.y; Wl[r][c4 + 2] = v.z; Wl[r][c4 + 3] = v.w;
  }
  __syncthreads();
  const int nl = tid >> 2;
  const int kc = (tid & 3) * 16;
  ushort o[48];
#pragma unroll
  for (int j = 0; j < 16; ++j) {
    float v = Wl[kc + j][nl];
    ushort h = bf16rn(v);
    float hf = __uint_as_float((uint)h << 16);
    ushort l = bf16rn(v - hf);
    o[3 * j] = h; o[3 * j + 1] = h; o[3 * j + 2] = l;
  }
  uint uu[24];
#pragma unroll
  for (int i = 0; i < 24; ++i) uu[i] = (uint)o[2 * i] | ((uint)o[2 * i + 1] << 16);
  uint4* dst = (uint4*)(dst_base + (size_t)(n0 + nl) * K3 + (size_t)(k0 + kc) * 3);
#pragma unroll
  for (int i = 0; i < 6; ++i)
    dst[i] = make_uint4(uu[4 * i], uu[4 * i + 1], uu[4 * i + 2], uu[4 * i + 3]);
}

// =====================================================================
// FUSED MFMA GEMM: out[16384x2560] = A'[16384xK3] @ W'[2560xK3]^T (+bias)
// One dispatch for all 5 weight matrices. 2560 blocks (10/CU), 128x128 tile,
// BK=32, 4 waves, 16x16x32 frags, global_load_lds(16B), double-buffered LDS.
// Per-block output segment (uniform): 0..2 -> Q2/K2/V2 bf16 [hi|lo] pairs
// (Q scaled 1/8), 3 -> ACC fp32 (+bias), 4 -> XL fp32.
// Bijective XCD swizzle (2560 % 8 == 0): each XCD gets 16 contiguous row
// panels x all 20 col panels -> A' panel fetched once per XCD.
// =====================================================================
__global__ __launch_bounds__(256) void k_gemm_fused(const ushort* __restrict__ Ap,
                                                    const ushort* __restrict__ Bp,
                                                    const float* __restrict__ bq,
                                                    const float* __restrict__ bk,
                                                    const float* __restrict__ bv,
                                                    const float* __restrict__ bsk,
                                                    ushort* __restrict__ QKV,
                                                    float* __restrict__ XL,
                                                    float* __restrict__ ACC) {
  __shared__ ushort Asm[2][128][32];
  __shared__ ushort Bsm[2][128][32];
  const int bid = blockIdx.x;                    // 0..2559
  const int swz = (bid & 7) * 320 + (bid >> 3);  // XCD-grouped, bijective
  const int by = swz / 20;                       // row panel 0..127
  const int bx = swz - by * 20;                  // col panel 0..19
  const int tid = threadIdx.x;
  const int lane = tid & 63;
  const int wv = tid >> 6;
  const int row0 = by * 128;
  const int col0 = bx * 128;
  const int srow = lane >> 2;
  const int sk8 = (lane & 3) * 8;
  const int lane16 = lane & 15;
  const int lq = lane >> 4;
  const int wm = (wv >> 1) * 64;
  const int wn = (wv & 1) * 64;

#define STAGE(buf, t)                                                                   \
  do {                                                                                  \
    const int k0s = (t) * 32;                                                           \
    _Pragma("unroll") for (int c = wv; c < 8; c += 4) {                                 \
      const ushort* ga = Ap + (size_t)(row0 + c * 16 + srow) * K3 + k0s + sk8;          \
      __builtin_amdgcn_global_load_lds(                                                 \
          (const __attribute__((address_space(1))) void*)ga,                            \
          (__attribute__((address_space(3))) void*)&Asm[buf][c * 16][0], 16, 0, 0);     \
      const ushort* gb = Bp + (size_t)(col0 + c * 16 + srow) * K3 + k0s + sk8;          \
      __builtin_amdgcn_global_load_lds(                                                 \
          (const __attribute__((address_space(1))) void*)gb,                            \
          (__attribute__((address_space(3))) void*)&Bsm[buf][c * 16][0], 16, 0, 0);     \
    }                                                                                   \
  } while (0)

  f32x4 acc[4][4];
#pragma unroll
  for (int m = 0; m < 4; ++m)
#pragma unroll
    for (int n = 0; n < 4; ++n) acc[m][n] = (f32x4){0.f, 0.f, 0.f, 0.f};

  STAGE(0, 0);
  int cur = 0;
  for (int t = 0; t < KSTEPS; ++t) {
    __syncthreads();  // staged tile t visible; prev reads done
    if (t + 1 < KSTEPS) STAGE(cur ^ 1, t + 1);
    bf16x8 av[4], bv8[4];
#pragma unroll
    for (int m = 0; m < 4; ++m)
      av[m] = *(const bf16x8*)&Asm[cur][wm + m * 16 + lane16][lq * 8];
#pragma unroll
    for (int n = 0; n < 4; ++n)
      bv8[n] = *(const bf16x8*)&Bsm[cur][wn + n * 16 + lane16][lq * 8];
#pragma unroll
    for (int m = 0; m < 4; ++m)
#pragma unroll
      for (int n = 0; n < 4; ++n)
        acc[m][n] = __builtin_amdgcn_mfma_f32_16x16x32_bf16(av[m], bv8[n], acc[m][n], 0, 0, 0);
    cur ^= 1;
  }

  const int seg = bx >> 2;  // 0..4, uniform per block
  const float scale = (seg == 0) ? 0.125f : 1.0f;
  const float* bptr = (seg == 0) ? bq : (seg == 1) ? bk : (seg == 2) ? bv
                    : (seg == 3) ? bsk : nullptr;
#pragma unroll
  for (int n = 0; n < 4; ++n) {
    const int col = col0 + wn + n * 16 + lane16;
    const int lcol = col & 511;
    const float bb = bptr ? bptr[lcol] : 0.0f;
    if (seg < 3) {
      ushort* C2 = QKV + (size_t)seg * 16777216u;
      const int hcol = ((lcol >> 6) << 7) + (lcol & 63);
#pragma unroll
      for (int m = 0; m < 4; ++m) {
        const int row = row0 + wm + m * 16 + lq * 4;
#pragma unroll
        for (int r = 0; r < 4; ++r) {
          float val = (acc[m][n][r] + bb) * scale;
          ushort hi = bf16rn(val);
          float hf = __uint_as_float((uint)hi << 16);
          ushort lo = bf16rn(val - hf);
          C2[(size_t)(row + r) * 1024 + hcol] = hi;
          C2[(size_t)(row + r) * 1024 + hcol + 64] = lo;
        }
      }
    } else {
      float* C = (seg == 3) ? ACC : XL;
#pragma unroll
      for (int m = 0; m < 4; ++m) {
        const int row = row0 + wm + m * 16 + lq * 4;
#pragma unroll
        for (int r = 0; r < 4; ++r)
          C[(size_t)(row + r) * DD + lcol] = acc[m][n][r] + bb;
      }
    }
  }
#undef STAGE
}

// =====================================================================
// MFMA flash attention. Grid (512 bh, 2 qb), 256 thr = 4 waves x 32 q.
// Swapped QK^T (A=K, B=Q) -> P forms in-register for PV.
// Q: [hi|hi|lo] segments (3-term w/ K [hi|lo|hi]); V: [hi|lo] pairs, P dup'd.
// ACC[q][h*64+d] += softmax(QK^T) @ V  (Q pre-scaled 1/8 in GEMM epilogue)
// =====================================================================
__global__ __launch_bounds__(256) void k_attn_mfma(const ushort* __restrict__ Q2,
                                                   const ushort* __restrict__ K2,
                                                   const ushort* __restrict__ V2,
                                                   float* __restrict__ ACC) {
  __shared__ ushort KL[64][136];  // [key][hi(64)|lo(64)] pairs, pad->conflict-free
  __shared__ ushort VT[64][138];  // [d][(vhi,vlo) per key], pad 138
  const int tid = threadIdx.x;
  const int lane = tid & 63;
  const int wv = tid >> 6;
  const int l16 = lane & 15;
  const int lq = lane >> 4;
  const int bh = blockIdx.x;
  const int qb = blockIdx.y;
  const int b = bh >> 3, h = bh & 7;
  const int hoff = h * 128;
  const int node0 = b * NN;
  const int q0w = qb * 128 + wv * 32;

  // Q B-fragments in registers: qf[n(q-group)][s(kstep of 192)]
  bf16x8 qf[2][6];
#pragma unroll
  for (int n = 0; n < 2; ++n) {
    const ushort* qrow = Q2 + (size_t)(node0 + q0w + n * 16 + l16) * 1024 + hoff;
#pragma unroll
    for (int s = 0; s < 6; ++s) {
      const int c = s * 4 + lq;                 // chunk 0..23 of [hi|hi|lo]
      const int phys = (c < 8) ? c : (c - 8);   // ->[hi(0..7)|lo(8..15)]
      qf[n][s] = *(const bf16x8*)(qrow + phys * 8);
    }
  }

  const int skey = tid >> 2;  // staging: key 0..63
  const int sq = tid & 3;
  const ushort* krow_base = K2 + (size_t)(node0 + skey) * 1024 + hoff;
  const ushort* vrow_base = V2 + (size_t)(node0 + skey) * 1024 + hoff;

  uint4 kreg[4], vh[2], vl[2];
#define LOADKV(kt)                                               \
  do {                                                           \
    const ushort* kr = krow_base + (size_t)(kt) * 64 * 1024;     \
    kreg[0] = *(const uint4*)(kr + (sq * 4 + 0) * 8);            \
    kreg[1] = *(const uint4*)(kr + (sq * 4 + 1) * 8);            \
    kreg[2] = *(const uint4*)(kr + (sq * 4 + 2) * 8);            \
    kreg[3] = *(const uint4*)(kr + (sq * 4 + 3) * 8);            \
    const ushort* vr = vrow_base + (size_t)(kt) * 64 * 1024;     \
    vh[0] = *(const uint4*)(vr + sq * 16);                       \
    vh[1] = *(const uint4*)(vr + sq * 16 + 8);                   \
    vl[0] = *(const uint4*)(vr + 64 + sq * 16);                  \
    vl[1] = *(const uint4*)(vr + 64 + sq * 16 + 8);              \
  } while (0)

  f32x4 o[2][4];
#pragma unroll
  for (int a = 0; a < 2; ++a)
#pragma unroll
    for (int c2 = 0; c2 < 4; ++c2) o[a][c2] = (f32x4){0.f, 0.f, 0.f, 0.f};
  float mrun[2] = {-INFINITY, -INFINITY};
  float lrun[2] = {0.f, 0.f};

  LOADKV(0);
  for (int kt = 0; kt < 4; ++kt) {
    // regs -> LDS (prev tile reads completed at loop-end barrier)
    *(uint4*)(&KL[skey][(sq * 4 + 0) * 8]) = kreg[0];
    *(uint4*)(&KL[skey][(sq * 4 + 1) * 8]) = kreg[1];
    *(uint4*)(&KL[skey][(sq * 4 + 2) * 8]) = kreg[2];
    *(uint4*)(&KL[skey][(sq * 4 + 3) * 8]) = kreg[3];
    {
      const ushort* hh = (const ushort*)vh;
      const ushort* llp = (const ushort*)vl;
#pragma unroll
      for (int j = 0; j < 16; ++j) {
        uint v = (uint)hh[j] | ((uint)llp[j] << 16);
        *((uint*)(&VT[sq * 16 + j][0]) + skey) = v;
      }
    }
    __syncthreads();
    if (kt < 3) LOADKV(kt + 1);  // T14: prefetch under compute

    // ---- QK^T (S^T): A=K [hi|lo|hi], B=Q regs ----
    f32x4 sa[4][2];
#pragma unroll
    for (int m = 0; m < 4; ++m) {
      sa[m][0] = (f32x4){0.f, 0.f, 0.f, 0.f};
      sa[m][1] = (f32x4){0.f, 0.f, 0.f, 0.f};
    }
#pragma unroll
    for (int s = 0; s < 6; ++s) {
      const int c = s * 4 + lq;
      const int phys = (c < 16) ? c : (c - 16);
      bf16x8 ak[4];
#pragma unroll
      for (int m = 0; m < 4; ++m)
        ak[m] = *(const bf16x8*)(&KL[m * 16 + l16][phys * 8]);
#pragma unroll
      for (int m = 0; m < 4; ++m) {
        sa[m][0] = __builtin_amdgcn_mfma_f32_16x16x32_bf16(ak[m], qf[0][s], sa[m][0], 0, 0, 0);
        sa[m][1] = __builtin_amdgcn_mfma_f32_16x16x32_bf16(ak[m], qf[1][s], sa[m][1], 0, 0, 0);
      }
    }

    // ---- online softmax (per lane: q = n*16+l16, keys = m*16+lq*4+r) ----
    bf16x8 pa[4][2];
#pragma unroll
    for (int n = 0; n < 2; ++n) {
      float mt = sa[0][n][0];
#pragma unroll
      for (int m = 0; m < 4; ++m)
#pragma unroll
        for (int r = 0; r < 4; ++r) mt = fmaxf(mt, sa[m][n][r]);
      mt = fmaxf(mt, __shfl_xor(mt, 16, 64));
      mt = fmaxf(mt, __shfl_xor(mt, 32, 64));
      const float mn = fmaxf(mrun[n], mt);
      const float sc = __expf(mrun[n] - mn);
      mrun[n] = mn;
      float rs = 0.f;
#pragma unroll
      for (int m = 0; m < 4; ++m)
#pragma unroll
        for (int r = 0; r < 4; ++r) {
          float p = __expf(sa[m][n][r] - mn);
          sa[m][n][r] = p;
          rs += p;
        }
      rs += __shfl_xor(rs, 16, 64);
      rs += __shfl_xor(rs, 32, 64);
      lrun[n] = lrun[n] * sc + rs;
      // rescale o rows of q-group n: o element r sits at q = n*16+lq*4+r
#pragma unroll
      for (int r = 0; r < 4; ++r) {
        const float scO = __shfl(sc, lq * 4 + r, 64);
#pragma unroll
        for (int np = 0; np < 4; ++np) o[n][np][r] *= scO;
      }
      // pack PV A-frags: pa[s4][n] = dup pairs of exp'd scores (keys s4*16+lq*4+r)
#pragma unroll
      for (int m = 0; m < 4; ++m) {
        ushort p0 = bf16rn(sa[m][n][0]);
        ushort p1 = bf16rn(sa[m][n][1]);
        ushort p2 = bf16rn(sa[m][n][2]);
        ushort p3 = bf16rn(sa[m][n][3]);
        bf16x8 tpk;
        tpk[0] = (short)p0; tpk[1] = (short)p0;
        tpk[2] = (short)p1; tpk[3] = (short)p1;
        tpk[4] = (short)p2; tpk[5] = (short)p2;
        tpk[6] = (short)p3; tpk[7] = (short)p3;
        pa[m][n] = tpk;
      }
    }

    // ---- PV: A=P(dup), B=VT (vhi,vlo pairs) ----
#pragma unroll
    for (int s4 = 0; s4 < 4; ++s4) {
#pragma unroll
      for (int np = 0; np < 4; ++np) {
        bf16x8 bvv = *(const bf16x8*)(&VT[np * 16 + l16][s4 * 32 + lq * 8]);
        o[0][np] = __builtin_amdgcn_mfma_f32_16x16x32_bf16(pa[s4][0], bvv, o[0][np], 0, 0, 0);
        o[1][np] = __builtin_amdgcn_mfma_f32_16x16x32_bf16(pa[s4][1], bvv, o[1][np], 0, 0, 0);
      }
    }
    __syncthreads();  // LDS reads done; next iter overwrites
  }

  // epilogue: O rows q = q0w + mp*16 + lq*4 + r; cols d = np*16 + l16
#pragma unroll
  for (int mp = 0; mp < 2; ++mp) {
    const float linv_l = 1.0f / lrun[mp];
#pragma unroll
    for (int r = 0; r < 4; ++r) {
      const float linv = __shfl(linv_l, lq * 4 + r, 64);
      float* dst = ACC + (size_t)(node0 + q0w + mp * 16 + lq * 4 + r) * DD + h * 64 + l16;
#pragma unroll
      for (int np = 0; np < 4; ++np)
        dst[np * 16] += o[mp][np][r] * linv;
    }
  }
#undef LOADKV
}

// =====================================================================
// GCN plumbing
// =====================================================================
__global__ __launch_bounds__(256) void k_degcnt(const int* __restrict__ ei,
                                                const float* __restrict__ w,
                                                float* __restrict__ deg,
                                                int* __restrict__ cnt) {
  int e = blockIdx.x * 256 + threadIdx.x;
  if (e < NE) {
    int d = ei[NE + e];
    atomicAdd(deg + d, w[e]);
    atomicAdd(cnt + d, 1);
  }
}

__global__ __launch_bounds__(256) void k_dinv(const float* __restrict__ deg,
                                              float* __restrict__ dinv) {
  int i = blockIdx.x * 256 + threadIdx.x;
  if (i < NNODE) dinv[i] = rsqrtf(deg[i] + 1.0f);
}

__global__ __launch_bounds__(256) void k_scan(const int* __restrict__ cnt,
                                              int* __restrict__ rowptr) {
  __shared__ int part[256];
  __shared__ int excl[257];
  const int t = threadIdx.x;
  const int base = t * 64;
  int s = 0;
  for (int j = 0; j < 64; ++j) s += cnt[base + j];
  part[t] = s;
  __syncthreads();
  if (t == 0) {
    int run = 0;
    for (int i = 0; i < 256; ++i) { excl[i] = run; run += part[i]; }
    excl[256] = run;
  }
  __syncthreads();
  int run = excl[t];
  for (int j = 0; j < 64; ++j) { rowptr[base + j] = run; run += cnt[base + j]; }
  if (t == 255) rowptr[NNODE] = excl[256];
}

__global__ __launch_bounds__(256) void k_fill(const int* __restrict__ ei,
                                              const float* __restrict__ w,
                                              const float* __restrict__ dinv,
                                              const int* __restrict__ rowptr,
                                              int* __restrict__ cursor,
                                              int* __restrict__ csrc,
                                              float* __restrict__ cnrm) {
  int e = blockIdx.x * 256 + threadIdx.x;
  if (e >= NE) return;
  int s = ei[e], d = ei[NE + e];
  int p = rowptr[d] + atomicAdd(cursor + d, 1);
  csrc[p] = s;
  cnrm[p] = dinv[s] * w[e] * dinv[d];
}

__global__ __launch_bounds__(256) void k_aggregate(const int* __restrict__ rowptr,
                                                   const int* __restrict__ csrc,
                                                   const float* __restrict__ cnrm,
                                                   const float* __restrict__ XL,
                                                   const float* __restrict__ dinv,
                                                   const float* __restrict__ bg,
                                                   float* __restrict__ ACC) {
  const int node = blockIdx.x * 2 + (threadIdx.x >> 7);
  const int c0 = (threadIdx.x & 127) << 2;
  float dv = dinv[node];
  dv *= dv;
  float4 a = *(const float4*)(XL + (size_t)node * DD + c0);
  a.x *= dv; a.y *= dv; a.z *= dv; a.w *= dv;
  const int beg = rowptr[node], end = rowptr[node + 1];
  int j = beg;
  for (; j + 1 < end; j += 2) {
    int s0 = csrc[j], s1 = csrc[j + 1];
    float n0 = cnrm[j], n1 = cnrm[j + 1];
    float4 u = *(const float4*)(XL + (size_t)s0 * DD + c0);
    float4 v = *(const float4*)(XL + (size_t)s1 * DD + c0);
    a.x = fmaf(u.x, n0, a.x); a.y = fmaf(u.y, n0, a.y);
    a.z = fmaf(u.z, n0, a.z); a.w = fmaf(u.w, n0, a.w);
    a.x = fmaf(v.x, n1, a.x); a.y = fmaf(v.y, n1, a.y);
    a.z = fmaf(v.z, n1, a.z); a.w = fmaf(v.w, n1, a.w);
  }
  if (j < end) {
    int s0 = csrc[j];
    float n0 = cnrm[j];
    float4 u = *(const float4*)(XL + (size_t)s0 * DD + c0);
    a.x = fmaf(u.x, n0, a.x); a.y = fmaf(u.y, n0, a.y);
    a.z = fmaf(u.z, n0, a.z); a.w = fmaf(u.w, n0, a.w);
  }
  float4 b = *(const float4*)(bg + c0);
  float* dst = ACC + (size_t)node * DD + c0;
  float4 c = *(const float4*)dst;
  c.x += a.x + b.x; c.y += a.y + b.y; c.z += a.z + b.z; c.w += a.w + b.w;
  *(float4*)dst = c;
}

// =====================================================================
// BatchNorm stats + finalize (BN + exact GELU)
// =====================================================================
__global__ __launch_bounds__(128) void k_colstats(const float* __restrict__ ACC,
                                                  float* __restrict__ cs,
                                                  float* __restrict__ csq) {
  const int col = blockIdx.y * 128 + threadIdx.x;
  const int r0 = blockIdx.x * 64;
  float s = 0.f, q = 0.f;
  for (int r = 0; r < 64; ++r) {
    float v = ACC[(size_t)(r0 + r) * DD + col];
    s += v;
    q = fmaf(v, v, q);
  }
  atomicAdd(cs + col, s);
  atomicAdd(csq + col, q);
}

__global__ __launch_bounds__(256) void k_finalize(const float* __restrict__ ACC,
                                                  const float* __restrict__ cs,
                                                  const float* __restrict__ csq,
                                                  const float* __restrict__ gamma,
                                                  const float* __restrict__ beta,
                                                  float* __restrict__ out) {
  const size_t i4 = (size_t)blockIdx.x * 256 + threadIdx.x;
  const int c = (int)(i4 & 127) << 2;
  float4 a = *(const float4*)(ACC + i4 * 4);
  float4 sv = *(const float4*)(cs + c);
  float4 qv = *(const float4*)(csq + c);
  float4 gv = *(const float4*)(gamma + c);
  float4 bv = *(const float4*)(beta + c);
  const float inv_n = 1.0f / (float)NNODE;
  float r[4];
  float av[4] = {a.x, a.y, a.z, a.w};
  float sa[4] = {sv.x, sv.y, sv.z, sv.w};
  float qa[4] = {qv.x, qv.y, qv.z, qv.w};
  float ga[4] = {gv.x, gv.y, gv.z, gv.w};
  float ba[4] = {bv.x, bv.y, bv.z, bv.w};
#pragma unroll
  for (int k = 0; k < 4; ++k) {
    float mu = sa[k] * inv_n;
    float var = qa[k] * inv_n - mu * mu;
    float g = (av[k] - mu) * rsqrtf(var + BNEPS) * ga[k] + ba[k];
    r[k] = 0.5f * g * (1.0f + erff(g * 0.70710678118654752f));
  }
  *(float4*)(out + i4 * 4) = make_float4(r[0], r[1], r[2], r[3]);
}

// =====================================================================
extern "C" void kernel_launch(void* const* d_in, const int* in_sizes, int n_in,
                              void* d_out, int out_size, void* d_ws, size_t ws_size,
                              hipStream_t stream) {
  const float* x   = (const float*)d_in[0];
  const int*   ei  = (const int*)d_in[1];
  const float* w   = (const float*)d_in[2];
  const float* Wq  = (const float*)d_in[4];
  const float* bq  = (const float*)d_in[5];
  const float* Wk  = (const float*)d_in[6];
  const float* bk  = (const float*)d_in[7];
  const float* Wv  = (const float*)d_in[8];
  const float* bv  = (const float*)d_in[9];
  const float* Wsk = (const float*)d_in[10];
  const float* bs  = (const float*)d_in[11];
  const float* Wg  = (const float*)d_in[12];
  const float* bg  = (const float*)d_in[13];
  const float* gam = (const float*)d_in[14];
  const float* bet = (const float*)d_in[15];

  float* wsf = (float*)d_ws;
  ushort* QKV = (ushort*)wsf;          // Q2|K2|V2 contiguous from offset 0
  ushort* Q2  = (ushort*)(wsf + OFF_Q);
  ushort* K2b = (ushort*)(wsf + OFF_K);
  ushort* V2b = (ushort*)(wsf + OFF_V);
  float* XL   = wsf + OFF_XL;
  float* ACC  = wsf + OFF_ACC;
  float* DEG  = wsf + OFF_DEG;
  float* CS   = wsf + OFF_CS;
  float* CSQ  = wsf + OFF_CSQ;
  int*   CNT  = (int*)(wsf + OFF_CNT);
  int*   CUR  = (int*)(wsf + OFF_CUR);
  float* DINV = wsf + OFF_DINV;
  int*   RP   = (int*)(wsf + OFF_RP);
  int*   CSRC = (int*)(wsf + OFF_CSRC);
  float* CNRM = wsf + OFF_CNRM;
  ushort* AP  = (ushort*)(wsf + OFF_AP);
  ushort* WP  = (ushort*)(wsf + OFF_WP);

  hipMemsetAsync(wsf + OFF_DEG, 0, (size_t)NZERO * 4, stream);

  // split-bf16 conversions (GEMM inputs)
  k_cvtA<<<4096, 256, 0, stream>>>(x, AP);
  k_cvtW<<<dim3(8, 8, 5), 256, 0, stream>>>(Wq, Wk, Wv, Wsk, Wg, WP);

  // ONE fused MFMA GEMM for all 5 weights (N=2560)
  k_gemm_fused<<<2560, 256, 0, stream>>>(AP, WP, bq, bk, bv, bs, QKV, XL, ACC);

  k_degcnt<<<NE / 256, 256, 0, stream>>>(ei, w, DEG, CNT);
  k_dinv<<<NNODE / 256, 256, 0, stream>>>(DEG, DINV);
  k_scan<<<1, 256, 0, stream>>>(CNT, RP);
  k_fill<<<NE / 256, 256, 0, stream>>>(ei, w, DINV, RP, CUR, CSRC, CNRM);

  k_attn_mfma<<<dim3(NB * HH, 2), 256, 0, stream>>>(Q2, K2b, V2b, ACC);
  k_aggregate<<<NNODE / 2, 256, 0, stream>>>(RP, CSRC, CNRM, XL, DINV, bg, ACC);

  k_colstats<<<dim3(NNODE / 64, DD / 128), 128, 0, stream>>>(ACC, CS, CSQ);
  k_finalize<<<(NNODE * DD / 4) / 256, 256, 0, stream>>>(ACC, CS, CSQ, gam, bet, (float*)d_out);
}

// Round 11
// 552.619 us; speedup vs baseline: 1.7379x; 1.0186x over previous
//
#include <hip/hip_runtime.h>
#include <math.h>

// Problem constants
#define NB    64
#define NN    256
#define NNODE 16384      // NB*NN
#define DD    512
#define HH    8
#define HDIM  64
#define NE    262144
#define BNEPS 1e-5f
#define K3    1536       // split-bf16 interleaved K (3 * 512)
#define KSTEPS 48        // K3 / 32

// ---------------- workspace layout (4-byte units) ----------------
#define OFF_Q    0ull
#define OFF_K    8388608ull
#define OFF_V    16777216ull
#define OFF_XL   25165824ull
#define OFF_ACC  33554432ull
#define OFF_DEG  41943040ull
#define OFF_CS   (OFF_DEG + NNODE)
#define OFF_CSQ  (OFF_CS + DD)
#define OFF_CNT  (OFF_CSQ + DD)
#define OFF_CUR  (OFF_CNT + NNODE)
#define NZERO    (NNODE + DD + DD + NNODE + NNODE)
#define OFF_DINV (OFF_CUR + NNODE)
#define OFF_RP   (OFF_DINV + NNODE)
#define OFF_CSRC (OFF_RP + NNODE + 1)
#define OFF_CNRM (OFF_CSRC + NE)
#define OFF_AP   42550280ull                  // bf16 A' [16384][1536]
#define OFF_WP   (OFF_AP + 12582912ull)       // bf16 W'  [5][512][1536] = [2560][1536]

typedef __attribute__((ext_vector_type(8))) short bf16x8;
typedef __attribute__((ext_vector_type(4))) float f32x4;

__device__ __forceinline__ ushort bf16rn(float v) {
  uint u = __float_as_uint(v);
  u += 0x7FFF + ((u >> 16) & 1);
  return (ushort)(u >> 16);
}

// =====================================================================
// fp32 -> split-bf16 conversions (GEMM inputs)
// A'[m][3k+0]=hi(x[m][k]) [3k+1]=lo [3k+2]=hi
// =====================================================================
__global__ __launch_bounds__(256) void k_cvtA(const float* __restrict__ x,
                                              ushort* __restrict__ Ap) {
  const size_t t = (size_t)blockIdx.x * 256 + threadIdx.x;
  const int row = (int)(t >> 6);
  const int kc = (int)(t & 63);
  const float* src = x + (size_t)row * DD + kc * 8;
  float4 v0 = *(const float4*)(src);
  float4 v1 = *(const float4*)(src + 4);
  float vv[8] = {v0.x, v0.y, v0.z, v0.w, v1.x, v1.y, v1.z, v1.w};
  ushort o[24];
#pragma unroll
  for (int j = 0; j < 8; ++j) {
    float v = vv[j];
    ushort h = bf16rn(v);
    float hf = __uint_as_float((uint)h << 16);
    ushort l = bf16rn(v - hf);
    o[3 * j] = h; o[3 * j + 1] = l; o[3 * j + 2] = h;
  }
  uint uu[12];
#pragma unroll
  for (int i = 0; i < 12; ++i) uu[i] = (uint)o[2 * i] | ((uint)o[2 * i + 1] << 16);
  uint4* dst = (uint4*)(Ap + (size_t)row * K3 + kc * 24);
  dst[0] = make_uint4(uu[0], uu[1], uu[2], uu[3]);
  dst[1] = make_uint4(uu[4], uu[5], uu[6], uu[7]);
  dst[2] = make_uint4(uu[8], uu[9], uu[10], uu[11]);
}

// W[k][n] -> W'[n][3k+0]=hi [3k+1]=hi [3k+2]=lo   (transposed, per weight z)
__global__ __launch_bounds__(256) void k_cvtW(const float* __restrict__ W0,
                                              const float* __restrict__ W1,
                                              const float* __restrict__ W2,
                                              const float* __restrict__ W3,
                                              const float* __restrict__ W4,
                                              ushort* __restrict__ Wp) {
  __shared__ float Wl[64][65];
  const float* const Wt[5] = {W0, W1, W2, W3, W4};
  const float* W = Wt[blockIdx.z];
  ushort* dst_base = Wp + (size_t)blockIdx.z * (DD * K3);
  const int k0 = blockIdx.x * 64, n0 = blockIdx.y * 64;
  const int tid = threadIdx.x;
#pragma unroll
  for (int i = 0; i < 4; ++i) {
    int r = (tid >> 4) + i * 16;
    int c4 = (tid & 15) * 4;
    float4 v = *(const float4*)(W + (size_t)(k0 + r) * DD + n0 + c4);
    Wl[r][c4 + 0] = v.x; Wl[r][c4 + 1] = v.y; Wl[r][c4 + 2] = v.z; Wl[r][c4 + 3] = v.w;
  }
  __syncthreads();
  const int nl = tid >> 2;
  const int kc = (tid & 3) * 16;
  ushort o[48];
#pragma unroll
  for (int j = 0; j < 16; ++j) {
    float v = Wl[kc + j][nl];
    ushort h = bf16rn(v);
    float hf = __uint_as_float((uint)h << 16);
    ushort l = bf16rn(v - hf);
    o[3 * j] = h; o[3 * j + 1] = h; o[3 * j + 2] = l;
  }
  uint uu[24];
#pragma unroll
  for (int i = 0; i < 24; ++i) uu[i] = (uint)o[2 * i] | ((uint)o[2 * i + 1] << 16);
  uint4* dst = (uint4*)(dst_base + (size_t)(n0 + nl) * K3 + (size_t)(k0 + kc) * 3);
#pragma unroll
  for (int i = 0; i < 6; ++i)
    dst[i] = make_uint4(uu[4 * i], uu[4 * i + 1], uu[4 * i + 2], uu[4 * i + 3]);
}

// =====================================================================
// FUSED MFMA GEMM: out[16384x2560] = A'[16384xK3] @ W'[2560xK3]^T (+bias)
// 2560 blocks, 128x128 tile, BK=32, 4 waves, 16x16x32 frags.
// T4 counted-vmcnt pipeline: 3 LDS buffers (48KB), 2-tiles-ahead prefetch via
// global_load_lds(16B); per K-step: s_waitcnt vmcnt(4) (tile t done, tile t+1's
// 4 per-wave loads stay in flight) + raw s_barrier, sched_barrier(0) fences on
// BOTH sides (raw s_barrier has no implicit memory fence — rule #18).
// =====================================================================
__global__ __launch_bounds__(256) void k_gemm_fused(const ushort* __restrict__ Ap,
                                                    const ushort* __restrict__ Bp,
                                                    const float* __restrict__ bq,
                                                    const float* __restrict__ bk,
                                                    const float* __restrict__ bv,
                                                    const float* __restrict__ bsk,
                                                    ushort* __restrict__ QKV,
                                                    float* __restrict__ XL,
                                                    float* __restrict__ ACC) {
  __shared__ ushort Asm[3][128][32];
  __shared__ ushort Bsm[3][128][32];
  const int bid = blockIdx.x;                    // 0..2559
  const int swz = (bid & 7) * 320 + (bid >> 3);  // XCD-grouped, bijective
  const int by = swz / 20;                       // row panel 0..127
  const int bx = swz - by * 20;                  // col panel 0..19
  const int tid = threadIdx.x;
  const int lane = tid & 63;
  const int wv = tid >> 6;
  const int row0 = by * 128;
  const int col0 = bx * 128;
  const int srow = lane >> 2;
  const int sk8 = (lane & 3) * 8;
  const int lane16 = lane & 15;
  const int lq = lane >> 4;
  const int wm = (wv >> 1) * 64;
  const int wn = (wv & 1) * 64;

// 4 global_load_lds per wave per STAGE (2 c-iters x 2 loads)
#define STAGE(buf, t)                                                                   \
  do {                                                                                  \
    const int k0s = (t) * 32;                                                           \
    _Pragma("unroll") for (int c = wv; c < 8; c += 4) {                                 \
      const ushort* ga = Ap + (size_t)(row0 + c * 16 + srow) * K3 + k0s + sk8;          \
      __builtin_amdgcn_global_load_lds(                                                 \
          (const __attribute__((address_space(1))) void*)ga,                            \
          (__attribute__((address_space(3))) void*)&Asm[buf][c * 16][0], 16, 0, 0);     \
      const ushort* gb = Bp + (size_t)(col0 + c * 16 + srow) * K3 + k0s + sk8;          \
      __builtin_amdgcn_global_load_lds(                                                 \
          (const __attribute__((address_space(1))) void*)gb,                            \
          (__attribute__((address_space(3))) void*)&Bsm[buf][c * 16][0], 16, 0, 0);     \
    }                                                                                   \
  } while (0)

  f32x4 acc[4][4];
#pragma unroll
  for (int m = 0; m < 4; ++m)
#pragma unroll
    for (int n = 0; n < 4; ++n) acc[m][n] = (f32x4){0.f, 0.f, 0.f, 0.f};

  STAGE(0, 0);
  STAGE(1, 1);
  for (int t = 0; t < KSTEPS; ++t) {
    const int cur = t % 3;
    // wait tile t (oldest 4 loads); keep tile t+1's 4 loads in flight
    if (t + 1 < KSTEPS) {
      asm volatile("s_waitcnt vmcnt(4)" ::: "memory");
    } else {
      asm volatile("s_waitcnt vmcnt(0)" ::: "memory");
    }
    __builtin_amdgcn_sched_barrier(0);  // rule #18: pin the wait
    __builtin_amdgcn_s_barrier();       // all waves' tile-t loads landed
    __builtin_amdgcn_sched_barrier(0);  // no ds_read hoisting above barrier
    if (t + 2 < KSTEPS) STAGE((t + 2) % 3, t + 2);
    bf16x8 av[4], bv8[4];
#pragma unroll
    for (int m = 0; m < 4; ++m)
      av[m] = *(const bf16x8*)&Asm[cur][wm + m * 16 + lane16][lq * 8];
#pragma unroll
    for (int n = 0; n < 4; ++n)
      bv8[n] = *(const bf16x8*)&Bsm[cur][wn + n * 16 + lane16][lq * 8];
#pragma unroll
    for (int m = 0; m < 4; ++m)
#pragma unroll
      for (int n = 0; n < 4; ++n)
        acc[m][n] = __builtin_amdgcn_mfma_f32_16x16x32_bf16(av[m], bv8[n], acc[m][n], 0, 0, 0);
  }

  const int seg = bx >> 2;  // 0..4, uniform per block
  const float scale = (seg == 0) ? 0.125f : 1.0f;
  const float* bptr = (seg == 0) ? bq : (seg == 1) ? bk : (seg == 2) ? bv
                    : (seg == 3) ? bsk : nullptr;
#pragma unroll
  for (int n = 0; n < 4; ++n) {
    const int col = col0 + wn + n * 16 + lane16;
    const int lcol = col & 511;
    const float bb = bptr ? bptr[lcol] : 0.0f;
    if (seg < 3) {
      ushort* C2 = QKV + (size_t)seg * 16777216u;
      const int hcol = ((lcol >> 6) << 7) + (lcol & 63);
#pragma unroll
      for (int m = 0; m < 4; ++m) {
        const int row = row0 + wm + m * 16 + lq * 4;
#pragma unroll
        for (int r = 0; r < 4; ++r) {
          float val = (acc[m][n][r] + bb) * scale;
          ushort hi = bf16rn(val);
          float hf = __uint_as_float((uint)hi << 16);
          ushort lo = bf16rn(val - hf);
          C2[(size_t)(row + r) * 1024 + hcol] = hi;
          C2[(size_t)(row + r) * 1024 + hcol + 64] = lo;
        }
      }
    } else {
      float* C = (seg == 3) ? ACC : XL;
#pragma unroll
      for (int m = 0; m < 4; ++m) {
        const int row = row0 + wm + m * 16 + lq * 4;
#pragma unroll
        for (int r = 0; r < 4; ++r)
          C[(size_t)(row + r) * DD + lcol] = acc[m][n][r] + bb;
      }
    }
  }
#undef STAGE
}

// =====================================================================
// MFMA flash attention. Grid (512 bh, 2 qb), 256 thr = 4 waves x 32 q.
// Swapped QK^T (A=K, B=Q) -> P forms in-register for PV.
// =====================================================================
__global__ __launch_bounds__(256) void k_attn_mfma(const ushort* __restrict__ Q2,
                                                   const ushort* __restrict__ K2,
                                                   const ushort* __restrict__ V2,
                                                   float* __restrict__ ACC) {
  __shared__ ushort KL[64][136];
  __shared__ ushort VT[64][138];
  const int tid = threadIdx.x;
  const int lane = tid & 63;
  const int wv = tid >> 6;
  const int l16 = lane & 15;
  const int lq = lane >> 4;
  const int bh = blockIdx.x;
  const int qb = blockIdx.y;
  const int b = bh >> 3, h = bh & 7;
  const int hoff = h * 128;
  const int node0 = b * NN;
  const int q0w = qb * 128 + wv * 32;

  bf16x8 qf[2][6];
#pragma unroll
  for (int n = 0; n < 2; ++n) {
    const ushort* qrow = Q2 + (size_t)(node0 + q0w + n * 16 + l16) * 1024 + hoff;
#pragma unroll
    for (int s = 0; s < 6; ++s) {
      const int c = s * 4 + lq;
      const int phys = (c < 8) ? c : (c - 8);
      qf[n][s] = *(const bf16x8*)(qrow + phys * 8);
    }
  }

  const int skey = tid >> 2;
  const int sq = tid & 3;
  const ushort* krow_base = K2 + (size_t)(node0 + skey) * 1024 + hoff;
  const ushort* vrow_base = V2 + (size_t)(node0 + skey) * 1024 + hoff;

  uint4 kreg[4], vh[2], vl[2];
#define LOADKV(kt)                                               \
  do {                                                           \
    const ushort* kr = krow_base + (size_t)(kt) * 64 * 1024;     \
    kreg[0] = *(const uint4*)(kr + (sq * 4 + 0) * 8);            \
    kreg[1] = *(const uint4*)(kr + (sq * 4 + 1) * 8);            \
    kreg[2] = *(const uint4*)(kr + (sq * 4 + 2) * 8);            \
    kreg[3] = *(const uint4*)(kr + (sq * 4 + 3) * 8);            \
    const ushort* vr = vrow_base + (size_t)(kt) * 64 * 1024;     \
    vh[0] = *(const uint4*)(vr + sq * 16);                       \
    vh[1] = *(const uint4*)(vr + sq * 16 + 8);                   \
    vl[0] = *(const uint4*)(vr + 64 + sq * 16);                  \
    vl[1] = *(const uint4*)(vr + 64 + sq * 16 + 8);              \
  } while (0)

  f32x4 o[2][4];
#pragma unroll
  for (int a = 0; a < 2; ++a)
#pragma unroll
    for (int c2 = 0; c2 < 4; ++c2) o[a][c2] = (f32x4){0.f, 0.f, 0.f, 0.f};
  float mrun[2] = {-INFINITY, -INFINITY};
  float lrun[2] = {0.f, 0.f};

  LOADKV(0);
  for (int kt = 0; kt < 4; ++kt) {
    *(uint4*)(&KL[skey][(sq * 4 + 0) * 8]) = kreg[0];
    *(uint4*)(&KL[skey][(sq * 4 + 1) * 8]) = kreg[1];
    *(uint4*)(&KL[skey][(sq * 4 + 2) * 8]) = kreg[2];
    *(uint4*)(&KL[skey][(sq * 4 + 3) * 8]) = kreg[3];
    {
      const ushort* hh = (const ushort*)vh;
      const ushort* llp = (const ushort*)vl;
#pragma unroll
      for (int j = 0; j < 16; ++j) {
        uint v = (uint)hh[j] | ((uint)llp[j] << 16);
        *((uint*)(&VT[sq * 16 + j][0]) + skey) = v;
      }
    }
    __syncthreads();
    if (kt < 3) LOADKV(kt + 1);

    f32x4 sa[4][2];
#pragma unroll
    for (int m = 0; m < 4; ++m) {
      sa[m][0] = (f32x4){0.f, 0.f, 0.f, 0.f};
      sa[m][1] = (f32x4){0.f, 0.f, 0.f, 0.f};
    }
#pragma unroll
    for (int s = 0; s < 6; ++s) {
      const int c = s * 4 + lq;
      const int phys = (c < 16) ? c : (c - 16);
      bf16x8 ak[4];
#pragma unroll
      for (int m = 0; m < 4; ++m)
        ak[m] = *(const bf16x8*)(&KL[m * 16 + l16][phys * 8]);
#pragma unroll
      for (int m = 0; m < 4; ++m) {
        sa[m][0] = __builtin_amdgcn_mfma_f32_16x16x32_bf16(ak[m], qf[0][s], sa[m][0], 0, 0, 0);
        sa[m][1] = __builtin_amdgcn_mfma_f32_16x16x32_bf16(ak[m], qf[1][s], sa[m][1], 0, 0, 0);
      }
    }

    bf16x8 pa[4][2];
#pragma unroll
    for (int n = 0; n < 2; ++n) {
      float mt = sa[0][n][0];
#pragma unroll
      for (int m = 0; m < 4; ++m)
#pragma unroll
        for (int r = 0; r < 4; ++r) mt = fmaxf(mt, sa[m][n][r]);
      mt = fmaxf(mt, __shfl_xor(mt, 16, 64));
      mt = fmaxf(mt, __shfl_xor(mt, 32, 64));
      const float mn = fmaxf(mrun[n], mt);
      const float sc = __expf(mrun[n] - mn);
      mrun[n] = mn;
      float rs = 0.f;
#pragma unroll
      for (int m = 0; m < 4; ++m)
#pragma unroll
        for (int r = 0; r < 4; ++r) {
          float p = __expf(sa[m][n][r] - mn);
          sa[m][n][r] = p;
          rs += p;
        }
      rs += __shfl_xor(rs, 16, 64);
      rs += __shfl_xor(rs, 32, 64);
      lrun[n] = lrun[n] * sc + rs;
#pragma unroll
      for (int r = 0; r < 4; ++r) {
        const float scO = __shfl(sc, lq * 4 + r, 64);
#pragma unroll
        for (int np = 0; np < 4; ++np) o[n][np][r] *= scO;
      }
#pragma unroll
      for (int m = 0; m < 4; ++m) {
        ushort p0 = bf16rn(sa[m][n][0]);
        ushort p1 = bf16rn(sa[m][n][1]);
        ushort p2 = bf16rn(sa[m][n][2]);
        ushort p3 = bf16rn(sa[m][n][3]);
        bf16x8 tpk;
        tpk[0] = (short)p0; tpk[1] = (short)p0;
        tpk[2] = (short)p1; tpk[3] = (short)p1;
        tpk[4] = (short)p2; tpk[5] = (short)p2;
        tpk[6] = (short)p3; tpk[7] = (short)p3;
        pa[m][n] = tpk;
      }
    }

#pragma unroll
    for (int s4 = 0; s4 < 4; ++s4) {
#pragma unroll
      for (int np = 0; np < 4; ++np) {
        bf16x8 bvv = *(const bf16x8*)(&VT[np * 16 + l16][s4 * 32 + lq * 8]);
        o[0][np] = __builtin_amdgcn_mfma_f32_16x16x32_bf16(pa[s4][0], bvv, o[0][np], 0, 0, 0);
        o[1][np] = __builtin_amdgcn_mfma_f32_16x16x32_bf16(pa[s4][1], bvv, o[1][np], 0, 0, 0);
      }
    }
    __syncthreads();
  }

#pragma unroll
  for (int mp = 0; mp < 2; ++mp) {
    const float linv_l = 1.0f / lrun[mp];
#pragma unroll
    for (int r = 0; r < 4; ++r) {
      const float linv = __shfl(linv_l, lq * 4 + r, 64);
      float* dst = ACC + (size_t)(node0 + q0w + mp * 16 + lq * 4 + r) * DD + h * 64 + l16;
#pragma unroll
      for (int np = 0; np < 4; ++np)
        dst[np * 16] += o[mp][np][r] * linv;
    }
  }
#undef LOADKV
}

// =====================================================================
// GCN plumbing
// =====================================================================
__global__ __launch_bounds__(256) void k_degcnt(const int* __restrict__ ei,
                                                const float* __restrict__ w,
                                                float* __restrict__ deg,
                                                int* __restrict__ cnt) {
  int e = blockIdx.x * 256 + threadIdx.x;
  if (e < NE) {
    int d = ei[NE + e];
    atomicAdd(deg + d, w[e]);
    atomicAdd(cnt + d, 1);
  }
}

__global__ __launch_bounds__(256) void k_dinv(const float* __restrict__ deg,
                                              float* __restrict__ dinv) {
  int i = blockIdx.x * 256 + threadIdx.x;
  if (i < NNODE) dinv[i] = rsqrtf(deg[i] + 1.0f);
}

__global__ __launch_bounds__(256) void k_scan(const int* __restrict__ cnt,
                                              int* __restrict__ rowptr) {
  __shared__ int part[256];
  __shared__ int excl[257];
  const int t = threadIdx.x;
  const int base = t * 64;
  int s = 0;
  for (int j = 0; j < 64; ++j) s += cnt[base + j];
  part[t] = s;
  __syncthreads();
  if (t == 0) {
    int run = 0;
    for (int i = 0; i < 256; ++i) { excl[i] = run; run += part[i]; }
    excl[256] = run;
  }
  __syncthreads();
  int run = excl[t];
  for (int j = 0; j < 64; ++j) { rowptr[base + j] = run; run += cnt[base + j]; }
  if (t == 255) rowptr[NNODE] = excl[256];
}

__global__ __launch_bounds__(256) void k_fill(const int* __restrict__ ei,
                                              const float* __restrict__ w,
                                              const float* __restrict__ dinv,
                                              const int* __restrict__ rowptr,
                                              int* __restrict__ cursor,
                                              int* __restrict__ csrc,
                                              float* __restrict__ cnrm) {
  int e = blockIdx.x * 256 + threadIdx.x;
  if (e >= NE) return;
  int s = ei[e], d = ei[NE + e];
  int p = rowptr[d] + atomicAdd(cursor + d, 1);
  csrc[p] = s;
  cnrm[p] = dinv[s] * w[e] * dinv[d];
}

__global__ __launch_bounds__(256) void k_aggregate(const int* __restrict__ rowptr,
                                                   const int* __restrict__ csrc,
                                                   const float* __restrict__ cnrm,
                                                   const float* __restrict__ XL,
                                                   const float* __restrict__ dinv,
                                                   const float* __restrict__ bg,
                                                   float* __restrict__ ACC) {
  const int node = blockIdx.x * 2 + (threadIdx.x >> 7);
  const int c0 = (threadIdx.x & 127) << 2;
  float dv = dinv[node];
  dv *= dv;
  float4 a = *(const float4*)(XL + (size_t)node * DD + c0);
  a.x *= dv; a.y *= dv; a.z *= dv; a.w *= dv;
  const int beg = rowptr[node], end = rowptr[node + 1];
  int j = beg;
  for (; j + 1 < end; j += 2) {
    int s0 = csrc[j], s1 = csrc[j + 1];
    float n0 = cnrm[j], n1 = cnrm[j + 1];
    float4 u = *(const float4*)(XL + (size_t)s0 * DD + c0);
    float4 v = *(const float4*)(XL + (size_t)s1 * DD + c0);
    a.x = fmaf(u.x, n0, a.x); a.y = fmaf(u.y, n0, a.y);
    a.z = fmaf(u.z, n0, a.z); a.w = fmaf(u.w, n0, a.w);
    a.x = fmaf(v.x, n1, a.x); a.y = fmaf(v.y, n1, a.y);
    a.z = fmaf(v.z, n1, a.z); a.w = fmaf(v.w, n1, a.w);
  }
  if (j < end) {
    int s0 = csrc[j];
    float n0 = cnrm[j];
    float4 u = *(const float4*)(XL + (size_t)s0 * DD + c0);
    a.x = fmaf(u.x, n0, a.x); a.y = fmaf(u.y, n0, a.y);
    a.z = fmaf(u.z, n0, a.z); a.w = fmaf(u.w, n0, a.w);
  }
  float4 b = *(const float4*)(bg + c0);
  float* dst = ACC + (size_t)node * DD + c0;
  float4 c = *(const float4*)dst;
  c.x += a.x + b.x; c.y += a.y + b.y; c.z += a.z + b.z; c.w += a.w + b.w;
  *(float4*)dst = c;
}

// =====================================================================
// BatchNorm stats + finalize (BN + exact GELU)
// =====================================================================
__global__ __launch_bounds__(128) void k_colstats(const float* __restrict__ ACC,
                                                  float* __restrict__ cs,
                                                  float* __restrict__ csq) {
  const int col = blockIdx.y * 128 + threadIdx.x;
  const int r0 = blockIdx.x * 64;
  float s = 0.f, q = 0.f;
  for (int r = 0; r < 64; ++r) {
    float v = ACC[(size_t)(r0 + r) * DD + col];
    s += v;
    q = fmaf(v, v, q);
  }
  atomicAdd(cs + col, s);
  atomicAdd(csq + col, q);
}

__global__ __launch_bounds__(256) void k_finalize(const float* __restrict__ ACC,
                                                  const float* __restrict__ cs,
                                                  const float* __restrict__ csq,
                                                  const float* __restrict__ gamma,
                                                  const float* __restrict__ beta,
                                                  float* __restrict__ out) {
  const size_t i4 = (size_t)blockIdx.x * 256 + threadIdx.x;
  const int c = (int)(i4 & 127) << 2;
  float4 a = *(const float4*)(ACC + i4 * 4);
  float4 sv = *(const float4*)(cs + c);
  float4 qv = *(const float4*)(csq + c);
  float4 gv = *(const float4*)(gamma + c);
  float4 bv = *(const float4*)(beta + c);
  const float inv_n = 1.0f / (float)NNODE;
  float r[4];
  float av[4] = {a.x, a.y, a.z, a.w};
  float sa[4] = {sv.x, sv.y, sv.z, sv.w};
  float qa[4] = {qv.x, qv.y, qv.z, qv.w};
  float ga[4] = {gv.x, gv.y, gv.z, gv.w};
  float ba[4] = {bv.x, bv.y, bv.z, bv.w};
#pragma unroll
  for (int k = 0; k < 4; ++k) {
    float mu = sa[k] * inv_n;
    float var = qa[k] * inv_n - mu * mu;
    float g = (av[k] - mu) * rsqrtf(var + BNEPS) * ga[k] + ba[k];
    r[k] = 0.5f * g * (1.0f + erff(g * 0.70710678118654752f));
  }
  *(float4*)(out + i4 * 4) = make_float4(r[0], r[1], r[2], r[3]);
}

// =====================================================================
extern "C" void kernel_launch(void* const* d_in, const int* in_sizes, int n_in,
                              void* d_out, int out_size, void* d_ws, size_t ws_size,
                              hipStream_t stream) {
  const float* x   = (const float*)d_in[0];
  const int*   ei  = (const int*)d_in[1];
  const float* w   = (const float*)d_in[2];
  const float* Wq  = (const float*)d_in[4];
  const float* bq  = (const float*)d_in[5];
  const float* Wk  = (const float*)d_in[6];
  const float* bk  = (const float*)d_in[7];
  const float* Wv  = (const float*)d_in[8];
  const float* bv  = (const float*)d_in[9];
  const float* Wsk = (const float*)d_in[10];
  const float* bs  = (const float*)d_in[11];
  const float* Wg  = (const float*)d_in[12];
  const float* bg  = (const float*)d_in[13];
  const float* gam = (const float*)d_in[14];
  const float* bet = (const float*)d_in[15];

  float* wsf = (float*)d_ws;
  ushort* QKV = (ushort*)wsf;          // Q2|K2|V2 contiguous from offset 0
  ushort* Q2  = (ushort*)(wsf + OFF_Q);
  ushort* K2b = (ushort*)(wsf + OFF_K);
  ushort* V2b = (ushort*)(wsf + OFF_V);
  float* XL   = wsf + OFF_XL;
  float* ACC  = wsf + OFF_ACC;
  float* DEG  = wsf + OFF_DEG;
  float* CS   = wsf + OFF_CS;
  float* CSQ  = wsf + OFF_CSQ;
  int*   CNT  = (int*)(wsf + OFF_CNT);
  int*   CUR  = (int*)(wsf + OFF_CUR);
  float* DINV = wsf + OFF_DINV;
  int*   RP   = (int*)(wsf + OFF_RP);
  int*   CSRC = (int*)(wsf + OFF_CSRC);
  float* CNRM = wsf + OFF_CNRM;
  ushort* AP  = (ushort*)(wsf + OFF_AP);
  ushort* WP  = (ushort*)(wsf + OFF_WP);

  hipMemsetAsync(wsf + OFF_DEG, 0, (size_t)NZERO * 4, stream);

  // split-bf16 conversions (GEMM inputs)
  k_cvtA<<<4096, 256, 0, stream>>>(x, AP);
  k_cvtW<<<dim3(8, 8, 5), 256, 0, stream>>>(Wq, Wk, Wv, Wsk, Wg, WP);

  // ONE fused MFMA GEMM for all 5 weights (N=2560)
  k_gemm_fused<<<2560, 256, 0, stream>>>(AP, WP, bq, bk, bv, bs, QKV, XL, ACC);

  k_degcnt<<<NE / 256, 256, 0, stream>>>(ei, w, DEG, CNT);
  k_dinv<<<NNODE / 256, 256, 0, stream>>>(DEG, DINV);
  k_scan<<<1, 256, 0, stream>>>(CNT, RP);
  k_fill<<<NE / 256, 256, 0, stream>>>(ei, w, DINV, RP, CUR, CSRC, CNRM);

  k_attn_mfma<<<dim3(NB * HH, 2), 256, 0, stream>>>(Q2, K2b, V2b, ACC);
  k_aggregate<<<NNODE / 2, 256, 0, stream>>>(RP, CSRC, CNRM, XL, DINV, bg, ACC);

  k_colstats<<<dim3(NNODE / 64, DD / 128), 128, 0, stream>>>(ACC, CS, CSQ);
  k_finalize<<<(NNODE * DD / 4) / 256, 256, 0, stream>>>(ACC, CS, CSQ, gam, bet, (float*)d_out);
}